// Round 9
// baseline (1415.774 us; speedup 1.0000x reference)
//
#include <hip/hip_runtime.h>

// FSU-MGU cell: exact integer reimplementation.
// Gate(b,c,t) = sum_w popc( (bits_w & pos_w) | (~bits_w & neg_w) ) + D'(t,c)
// x-gates (input-static) precomputed for ALL t in setup phase D, stored packed
// (u16 lo = i_f gate + 2048, hi = i_n gate + 2048) into the x-mask region of
// the masks buffer (exact-fit reuse). Main loop: h-gates only (LDS-staged,
// double-buffered), ONE barrier/step, fence-free tagged-slot h exchange.

#define NBLK 256
#define NTHR 1024

// workspace layout (bytes); [0,4096) and hw region zeroed each call
#define WS_BAR_SUB   0u
#define WS_BAR_MST   1024u
#define WS_BAR_FLG   2048u
#define WS_RNGW   8192u
#define WS_RNGWI  9216u
#define WS_RNGM   10240u
#define WS_SRCB   12288u       // 4096 u16
#define WS_SRCW   20480u       // 4096*1024 u16 (end 8,409,088)
#define WS_XP     8409088u     // 64*128*32 u32 (end 9,457,664)
#define WS_HW     9457664u     // 2 region * 4 bg * 64 jt * 16 u64 = 65,536
#define WS_DT     9523200u     // 64*4096 i32 (end 10,571,776)
#define WS_MASKS  10571776u    // 64*4096*32 u64 (end 77,680,640)
// xg(t) overwrites cols [0,2048) of t-slab: 131072 u32 per slab, exact fit.

struct SRng {
  unsigned mt[3][624];
  unsigned yb[3][624];
  unsigned draws[3][1248];
  int perm[3][256];
};
struct SC {
  unsigned short rows[16][1028];
  int rngw[64];
  int rngwi[64];
};
struct SD {
  unsigned xst[32*32];                 // phase D: staged x rows (broadcast reads)
};
struct SL {
  unsigned long long hmask[2][32*34];  // h-gate masks, double-buffered
  unsigned short hrow16[2][32*68];     // h bits u16[row][jt'], double-buffered
  int rngm[16];
};
union SU { SRng r; SC c; SD d; SL l; };

__device__ __forceinline__ unsigned mt_temper(unsigned y){
  y ^= y >> 11;
  y ^= (y << 7)  & 0x9d2c5680u;
  y ^= (y << 15) & 0xefc60000u;
  y ^= y >> 18;
  return y;
}

__device__ void mt_regen_serial(unsigned* mt){
  for (int i = 0; i < 624; i++){
    unsigned y = (mt[i] & 0x80000000u) | (mt[(i+1)%624] & 0x7fffffffu);
    mt[i] = mt[(i+397)%624] ^ (y >> 1) ^ ((y & 1u) ? 0x9908b0dfu : 0u);
  }
}

// numpy legacy RandomState: init_genrand seeding + Fisher-Yates with masked rejection.
__device__ void rng_gen(SU* sm, int* rngw, int* rngwi, int* rngm){
  const int tid = threadIdx.x;
  const int wv = tid >> 6, lane = tid & 63;
  const bool act = (wv < 3);
  if (act && lane == 0){
    unsigned* mt = sm->r.mt[wv];
    mt[0] = (unsigned)wv;  // seeds 0,1,2
    for (int i = 1; i < 624; i++)
      mt[i] = 1812433253u * (mt[i-1] ^ (mt[i-1] >> 30)) + (unsigned)i;
  }
  __syncthreads();
  for (int r = 0; r < 2; r++){
    if (act){
      unsigned* mt = sm->r.mt[wv]; unsigned* yb = sm->r.yb[wv];
      for (int i = lane; i < 623; i += 64)
        yb[i] = (mt[i] & 0x80000000u) | (mt[i+1] & 0x7fffffffu);
    }
    __syncthreads();
    if (act){
      unsigned* mt = sm->r.mt[wv]; unsigned* yb = sm->r.yb[wv];
      for (int i = lane; i < 227; i += 64){
        unsigned y = yb[i];
        mt[i] = mt[i+397] ^ (y >> 1) ^ ((y & 1u) ? 0x9908b0dfu : 0u);
      }
    }
    __syncthreads();
    if (act){
      unsigned* mt = sm->r.mt[wv]; unsigned* yb = sm->r.yb[wv];
      for (int i = 227 + lane; i < 454; i += 64){
        unsigned y = yb[i];
        mt[i] = mt[i-227] ^ (y >> 1) ^ ((y & 1u) ? 0x9908b0dfu : 0u);
      }
    }
    __syncthreads();
    if (act){
      unsigned* mt = sm->r.mt[wv]; unsigned* yb = sm->r.yb[wv];
      for (int i = 454 + lane; i < 624; i += 64){
        unsigned y = (i < 623) ? yb[i]
                   : ((mt[623] & 0x80000000u) | (mt[0] & 0x7fffffffu));
        mt[i] = mt[i-227] ^ (y >> 1) ^ ((y & 1u) ? 0x9908b0dfu : 0u);
      }
    }
    __syncthreads();
    if (act){
      unsigned* mt = sm->r.mt[wv];
      for (int i = lane; i < 624; i += 64)
        sm->r.draws[wv][r*624 + i] = mt_temper(mt[i]);
    }
    __syncthreads();
  }
  if (act && lane == 0){
    const int n = (wv == 2) ? 16 : 256;
    int* perm = sm->r.perm[wv];
    for (int i = 0; i < n; i++) perm[i] = i;
    int dp = 0, spos = 624;
    unsigned* mt = sm->r.mt[wv];
    for (int i = n - 1; i > 0; i--){
      unsigned mask = (unsigned)i;
      mask |= mask >> 1; mask |= mask >> 2; mask |= mask >> 4;
      mask |= mask >> 8; mask |= mask >> 16;
      unsigned v;
      do {
        unsigned d;
        if (dp < 1248) d = sm->r.draws[wv][dp++];
        else {
          if (spos >= 624){ mt_regen_serial(mt); spos = 0; }
          d = mt_temper(mt[spos++]);
        }
        v = d & mask;
      } while (v > (unsigned)i);
      int tmp = perm[i]; perm[i] = perm[v]; perm[v] = tmp;
    }
    int* dst = (wv == 0) ? rngw : (wv == 1) ? rngwi : rngm;
    for (int i = 0; i < n; i++) dst[i] = perm[i];
  }
}

// full-grid barrier WITH fences — setup phases only
__device__ __forceinline__ void gbar_full(unsigned char* ws, unsigned ep){
  __syncthreads();
  if (threadIdx.x == 0){
    __threadfence();
    unsigned* sub = (unsigned*)(ws + WS_BAR_SUB + (blockIdx.x & 7)*128);
    unsigned old = atomicAdd(sub, 1u);
    if (old == ep*32u - 1u){
      unsigned* mst = (unsigned*)(ws + WS_BAR_MST);
      unsigned mo = atomicAdd(mst, 1u);
      if (mo == ep*8u - 1u){
        for (int i = 0; i < 8; i++)
          __hip_atomic_store((unsigned*)(ws + WS_BAR_FLG + i*128), ep,
                             __ATOMIC_RELAXED, __HIP_MEMORY_SCOPE_AGENT);
      }
    }
    const unsigned* fl = (const unsigned*)(ws + WS_BAR_FLG + (blockIdx.x & 7)*128);
    while (__hip_atomic_load(fl, __ATOMIC_RELAXED, __HIP_MEMORY_SCOPE_AGENT) < ep)
      __builtin_amdgcn_s_sleep(8);
  }
  __syncthreads();
  __threadfence();
}

__device__ __forceinline__ int clampi(int v){
  v = v < -512 ? -512 : v;
  v = v >  512 ?  512 : v;
  return v;
}

// (x & p) | (~x & n)  ->  v_bfi_b32
__device__ __forceinline__ unsigned bfi(unsigned x, unsigned p, unsigned n){
  return (x & p) | (~x & n);
}

__global__ void __launch_bounds__(NTHR)
fsu_kernel(const float* __restrict__ x, const float* __restrict__ hx0,
           const float* __restrict__ wih, const float* __restrict__ bih,
           const float* __restrict__ whh, const float* __restrict__ bhh,
           float* __restrict__ out, unsigned char* __restrict__ ws)
{
  __shared__ SU sm;
  const int tid = threadIdx.x;
  const int bid = blockIdx.x;

  int* rngw  = (int*)(ws + WS_RNGW);
  int* rngwi = (int*)(ws + WS_RNGWI);
  int* rngm  = (int*)(ws + WS_RNGM);
  unsigned short* srcb = (unsigned short*)(ws + WS_SRCB);
  unsigned short* srcw = (unsigned short*)(ws + WS_SRCW);
  unsigned* xp   = (unsigned*)(ws + WS_XP);
  unsigned long long* hw = (unsigned long long*)(ws + WS_HW);
  int* Dt = (int*)(ws + WS_DT);
  unsigned long long* masks = (unsigned long long*)(ws + WS_MASKS);
  unsigned* xgpool = (unsigned*)(ws + WS_MASKS);   // u32 view; slab stride 262144

  // ---------- phase 0: RNG tables (block 0) || bit-pack + src build (others)
  if (bid == 0){
    rng_gen(&sm, rngw, rngwi, rngm);
  } else {
    const int gtid = (bid - 1)*NTHR + tid;
    const int lane = tid & 63;
    const int gw = gtid >> 6;
    const int nw = (NBLK-1)*(NTHR/64);
    const int nthr = (NBLK-1)*NTHR;
    for (int ch = gw; ch < 131072; ch += nw){            // x bits
      float v = x[(size_t)ch*64 + lane];
      unsigned long long bal = __ballot(v != 0.0f);
      if ((lane & 31) == 0) xp[ch*2 + (lane >> 5)] = (unsigned)(bal >> lane);
    }
    for (int idx = gtid; idx < 4096; idx += nthr){       // initial h slots (region 0, tag 0)
      int bg2 = idx >> 10, jt2 = (idx >> 4) & 63, rp2 = idx & 15;
      int r0 = bg2*32 + 2*rp2;
      unsigned v = 0;
      for (int j = 0; j < 16; j++){
        v |= (hx0[(size_t)r0*1024 + jt2*16 + j] != 0.0f) ? (1u<<j) : 0u;
        v |= (hx0[(size_t)(r0+1)*1024 + jt2*16 + j] != 0.0f) ? (1u<<(16+j)) : 0u;
      }
      hw[idx] = (unsigned long long)v;  // tag 0; flushed by gbar_full fence
    }
    for (int idx = gtid; idx < 4096*1024; idx += nthr){  // src = round((clip+1)*128)
      int c = idx >> 10, k = idx & 1023;
      float wv2 = (c < 2048) ? wih[(size_t)c*1024 + k] : whh[(size_t)(c - 2048)*1024 + k];
      float cl = fminf(fmaxf(wv2, -1.0f), 1.0f);
      srcw[idx] = (unsigned short)(int)rintf((cl + 1.0f)*0.5f*256.0f);
    }
    for (int c = gtid; c < 4096; c += nthr){
      float bv = (c < 2048) ? bih[c] : bhh[c - 2048];
      float cl = fminf(fmaxf(bv, -1.0f), 1.0f);
      srcb[c] = (unsigned short)(int)rintf((cl + 1.0f)*0.5f*256.0f);
    }
  }
  gbar_full(ws, 1u);

  // ---------- phase C: pos/neg masks + D' constants (popc(neg) folded in)
  {
    const int c0 = bid * 16;
    const unsigned* srcw32 = (const unsigned*)srcw;
    for (int q = tid; q < 16*512; q += NTHR){
      int r = q >> 9, w = q & 511;
      ((unsigned*)&sm.c.rows[r][0])[w] = srcw32[(size_t)(c0 + r)*512 + w];
    }
    if (tid < 64) sm.c.rngw[tid] = rngw[tid];
    if (tid >= 64 && tid < 128) sm.c.rngwi[tid - 64] = rngwi[tid - 64];
    __syncthreads();
    for (int row = tid; row < 1024; row += NTHR){   // (t, local col)
      int t = row >> 4, lc = row & 15, col = c0 + lc;
      int rp = sm.c.rngw[t], ri = sm.c.rngwi[t];
      int hi = rp > ri ? rp : ri;
      int lo1 = (rp < ri ? rp : ri) + 1;
      bool rihi = (ri >= rp);
      const unsigned* srow = (const unsigned*)&sm.c.rows[lc][0];
      unsigned long long* gdst = masks + ((size_t)t*4096 + col)*32;
      int cnti = 0, cntn = 0;
      for (int w = 0; w < 32; w++){
        unsigned pos = 0, neg = 0;
        #pragma unroll
        for (int i2 = 15; i2 >= 0; i2--){
          unsigned v2 = srow[w*16 + i2];
          int vH = (int)(v2 >> 16);
          int vL = (int)(v2 & 0xFFFFu);
          pos = (pos << 1) | ((unsigned)(hi - vH) >> 31);   // v > hi
          neg = (neg << 1) | ((unsigned)(vH - lo1) >> 31);  // v <= lo
          pos = (pos << 1) | ((unsigned)(hi - vL) >> 31);
          neg = (neg << 1) | ((unsigned)(vL - lo1) >> 31);
        }
        gdst[w] = (unsigned long long)pos | ((unsigned long long)neg << 32);
        cnti += rihi ? __popc(pos) : (32 - __popc(neg));    // count(src > ri)
        cntn += __popc(neg);
      }
      Dt[t*4096 + col] = 1024 - cnti - cntn + (((int)srcb[col] > rp) ? 1 : 0);
    }
  }
  gbar_full(ws, 2u);

  // ---------- phase D: precompute x-gates for all t into regs, then store
  {
    const int tD = bid >> 2, bq = bid & 3;
    {
      int b_l = tid >> 5, w = tid & 31;
      sm.d.xst[b_l*32 + w] = xp[((size_t)tD*128 + bq*32 + b_l)*32 + w];
    }
    __syncthreads();
    const int jcol = tid;
    int dA = Dt[tD*4096 + jcol] + 2048;          // gate i_f col
    int dB = Dt[tD*4096 + 1024 + jcol] + 2048;   // gate i_n col
    unsigned acc[32];
    #pragma unroll
    for (int b = 0; b < 32; b++) acc[b] = (unsigned)dA | ((unsigned)dB << 16);
    const uint4* mA = (const uint4*)(masks + ((size_t)tD*4096 + jcol)*32);
    const uint4* mB = (const uint4*)(masks + ((size_t)tD*4096 + 1024 + jcol)*32);
    for (int c = 0; c < 4; c++){
      uint4 a0 = mA[c*4+0], a1 = mA[c*4+1], a2 = mA[c*4+2], a3 = mA[c*4+3];
      uint4 g0 = mB[c*4+0], g1 = mB[c*4+1], g2 = mB[c*4+2], g3 = mB[c*4+3];
      #pragma unroll
      for (int b = 0; b < 32; b++){
        const uint4* xv = (const uint4*)&sm.d.xst[b*32 + c*8];
        uint4 x0 = xv[0], x1 = xv[1];
        unsigned sA =
            __popc(bfi(x0.x, a0.x, a0.y)) + __popc(bfi(x0.y, a0.z, a0.w)) +
            __popc(bfi(x0.z, a1.x, a1.y)) + __popc(bfi(x0.w, a1.z, a1.w)) +
            __popc(bfi(x1.x, a2.x, a2.y)) + __popc(bfi(x1.y, a2.z, a2.w)) +
            __popc(bfi(x1.z, a3.x, a3.y)) + __popc(bfi(x1.w, a3.z, a3.w));
        unsigned sB =
            __popc(bfi(x0.x, g0.x, g0.y)) + __popc(bfi(x0.y, g0.z, g0.w)) +
            __popc(bfi(x0.z, g1.x, g1.y)) + __popc(bfi(x0.w, g1.z, g1.w)) +
            __popc(bfi(x1.x, g2.x, g2.y)) + __popc(bfi(x1.y, g2.z, g2.w)) +
            __popc(bfi(x1.z, g3.x, g3.y)) + __popc(bfi(x1.w, g3.z, g3.w));
        acc[b] += sA + (sB << 16);
      }
    }
    gbar_full(ws, 3u);    // all x-mask reads complete grid-wide
    unsigned* xgst = xgpool + (size_t)tD*262144;
    #pragma unroll
    for (int b = 0; b < 32; b++)
      xgst[(size_t)(bq*32 + b)*1024 + jcol] = acc[b];
  }
  gbar_full(ws, 4u);

  // ---------- main recurrence
  const int jt = bid & 63, bg = bid >> 6;
  const int j0 = jt * 16, b0 = bg * 32;
  const int kh  = (tid >> 5) & 1;
  const int o   = ((tid >> 6) << 5) + (tid & 31);   // 0..511
  const int b_l = o >> 4, j_l = o & 15;
  const int bglob = b0 + b_l;
  const int w2lo = kh << 3;
  const int jcol = j0 + j_l;

  int hcur = (hx0[(size_t)bglob*1024 + jcol] != 0.0f) ? 1 : 0;
  int A1=0,A2=0,A3=0,A4=0,A5=0,A6=0;
  unsigned sr1=10u, sr2=10u, sr3=10u;
  int i1p=0,i1i=0,i2p=0,i2i=0,i3p=0,i3i=0;

  if (tid < 16) sm.l.rngm[tid] = rngm[tid];

  const unsigned* msrc = (const unsigned*)masks;
  int cur = 0;
  unsigned mreg[2];
  unsigned xg_cur, xg_nxt;
  int dhf, dhn, dh_nf, dh_nn;

  // ---- prime: stage t=0 hmask, initial h, xg/dh for t=0,1, mreg t=1
  {
    unsigned* mbuf = (unsigned*)sm.l.hmask[0];
    #pragma unroll
    for (int i = 0; i < 2; i++){
      int q = tid + i*NTHR;
      int r = q >> 6, qq = q & 63;
      int c = 2048 + (r >> 4)*1024 + j0 + (r & 15);
      mbuf[r*68 + qq] = msrc[((size_t)0*4096 + c)*64 + qq];
    }
    {
      unsigned long long v = __hip_atomic_load(&hw[(size_t)bg*1024 + tid],
                                               __ATOMIC_RELAXED,
                                               __HIP_MEMORY_SCOPE_AGENT);
      int jt_ = tid >> 4, rp_ = tid & 15;
      unsigned data = (unsigned)v;
      sm.l.hrow16[0][(2*rp_)*68 + jt_]   = (unsigned short)(data & 0xFFFFu);
      sm.l.hrow16[0][(2*rp_+1)*68 + jt_] = (unsigned short)(data >> 16);
    }
    xg_cur = xgpool[(size_t)0*262144 + (size_t)bglob*1024 + jcol];
    xg_nxt = xgpool[(size_t)1*262144 + (size_t)bglob*1024 + jcol];
    dhf   = Dt[0*4096 + 2048 + jcol];
    dhn   = Dt[0*4096 + 3072 + jcol];
    dh_nf = Dt[1*4096 + 2048 + jcol];
    dh_nn = Dt[1*4096 + 3072 + jcol];
    #pragma unroll
    for (int i = 0; i < 2; i++){
      int q = tid + i*NTHR;
      int r = q >> 6, qq = q & 63;
      int c = 2048 + (r >> 4)*1024 + j0 + (r & 15);
      mreg[i] = msrc[((size_t)1*4096 + c)*64 + qq];
    }
    __syncthreads();
  }

  for (int t = 0; t < 64; t++){
    const int par = t & 1;

    // ---- h-gate popc (half-K, bfi form) + wave-local combine
    int s2=0, s3=0;
    {
      const uint2* hrow = (const uint2*)&sm.l.hrow16[cur][b_l*68];
      const ulonglong2* m2p = (const ulonglong2*)&sm.l.hmask[cur][(0  + j_l)*34];
      const ulonglong2* m3p = (const ulonglong2*)&sm.l.hmask[cur][(16 + j_l)*34];
      #pragma unroll
      for (int w2i = 0; w2i < 8; w2i++){
        int w2 = w2lo + w2i;
        uint2 hv = hrow[w2];
        ulonglong2 c2 = m2p[w2];
        s2 += __popc(bfi(hv.x, (unsigned)c2.x, (unsigned)(c2.x >> 32)));
        s2 += __popc(bfi(hv.y, (unsigned)c2.y, (unsigned)(c2.y >> 32)));
        ulonglong2 d = m3p[w2];
        s3 += __popc(bfi(hv.x, (unsigned)d.x, (unsigned)(d.x >> 32)));
        s3 += __popc(bfi(hv.y, (unsigned)d.y, (unsigned)(d.y >> 32)));
      }
    }
    s2 += __shfl_xor(s2, 32);
    s3 += __shfl_xor(s3, 32);
    const int g_hf = dhf + s2;
    const int g_hn = dhn + s3;
    const int xgf = (int)(xg_cur & 0xFFFFu) - 2048;
    const int xgn = (int)(xg_cur >> 16) - 2048;

    // ---- FSU elementwise chain (exact, 2x-scaled ints; dup on l, l^32)
    int s1v = xgf + g_hf;
    A1 = clampi(A1 + 2*s1v - 2049);
    int fg_in = (A1 >= 2); A1 -= fg_in << 1;
    A2 = clampi(A2 + ((fg_in + 1) << 1));
    int fg = (A2 >= 4); A2 -= fg << 2;
    A3 = clampi(A3 + (g_hn << 1) - 1024);
    int hnb = (A3 >= 2); A3 -= hnb << 1;

    sr1 = ((sr1 >> 1) | ((unsigned)hnb << 3)) & 0xFu;
    int ng_prod;
    {
      int cv = __popc(sr1) << 2;
      int bp = cv > sm.l.rngm[i1p & 15];
      int bi = cv > sm.l.rngm[i1i & 15];
      ng_prod = fg ? bp : (1 - bi);
      i1p += fg; i1i += 1 - fg;
    }
    A4 = clampi(A4 + (xgn << 1) - 1024);
    int inb = (A4 >= 2); A4 -= inb << 1;
    A5 = clampi(A5 + ((inb + ng_prod) << 1) - 1);
    int ng = (A5 >= 2); A5 -= ng << 1;

    sr2 = ((sr2 >> 1) | ((unsigned)ng << 3)) & 0xFu;
    int fgi;
    {
      int cv = __popc(sr2) << 2;
      int bp = cv > sm.l.rngm[i2p & 15];
      int bi = cv > sm.l.rngm[i2i & 15];
      fgi = (1 - fg) ? bp : (1 - bi);
      i2p += 1 - fg; i2i += fg;
    }
    sr3 = ((sr3 >> 1) | ((unsigned)hcur << 3)) & 0xFu;
    int fgp;
    {
      int cv = __popc(sr3) << 2;
      int bp = cv > sm.l.rngm[i3p & 15];
      int bi = cv > sm.l.rngm[i3i & 15];
      fgp = fg ? bp : (1 - bi);
      i3p += fg; i3i += 1 - fg;
    }
    A6 = clampi(A6 + ((ng + fgi + fgp) << 1) - 2);
    int hy = (A6 >= 2); A6 -= hy << 1;
    hcur = hy;

    if (t < 63){
      unsigned long long bal = __ballot(hy);
      if ((tid & 63) == 0){
        unsigned data = (unsigned)bal;
        unsigned long long val = (unsigned long long)data
                               | ((unsigned long long)(unsigned)(t + 1) << 32);
        __hip_atomic_store(
            &hw[(((size_t)((par ^ 1)*4 + bg))*64 + jt)*16 + (tid >> 6)], val,
            __ATOMIC_RELAXED, __HIP_MEMORY_SCOPE_AGENT);
      }
    }
    if (kh == 0)
      out[(size_t)t*131072 + (size_t)bglob*1024 + jcol] = (float)hy;
    if (t == 63) break;

    // commit prefetched h-mask tile (t+1) into the other buffer
    {
      unsigned* mbuf = (unsigned*)sm.l.hmask[cur ^ 1];
      #pragma unroll
      for (int i = 0; i < 2; i++){
        int q = tid + i*NTHR;
        mbuf[(q >> 6)*68 + (q & 63)] = mreg[i];
      }
    }

    // rotate xg/dh; issue prefetches for t+2
    xg_cur = xg_nxt; dhf = dh_nf; dhn = dh_nn;
    if (t < 62){
      #pragma unroll
      for (int i = 0; i < 2; i++){
        int q = tid + i*NTHR;
        int r = q >> 6, qq = q & 63;
        int c = 2048 + (r >> 4)*1024 + j0 + (r & 15);
        mreg[i] = msrc[((size_t)(t+2)*4096 + c)*64 + qq];
      }
      xg_nxt = xgpool[(size_t)(t+2)*262144 + (size_t)bglob*1024 + jcol];
      dh_nf = Dt[(t+2)*4096 + 2048 + jcol];
      dh_nn = Dt[(t+2)*4096 + 3072 + jcol];
    }

    // pull h(t+1): one tagged slot per thread, tag-spin
    {
      const unsigned ep = (unsigned)(t + 1);
      const unsigned long long* slot =
          &hw[((size_t)((par ^ 1)*4 + bg))*1024 + tid];
      unsigned long long v = __hip_atomic_load(slot, __ATOMIC_RELAXED,
                                               __HIP_MEMORY_SCOPE_AGENT);
      while ((unsigned)(v >> 32) < ep){
        __builtin_amdgcn_s_sleep(2);
        v = __hip_atomic_load(slot, __ATOMIC_RELAXED,
                              __HIP_MEMORY_SCOPE_AGENT);
      }
      int jt_ = tid >> 4, rp_ = tid & 15;
      unsigned data = (unsigned)v;
      sm.l.hrow16[cur ^ 1][(2*rp_)*68 + jt_]   = (unsigned short)(data & 0xFFFFu);
      sm.l.hrow16[cur ^ 1][(2*rp_+1)*68 + jt_] = (unsigned short)(data >> 16);
    }
    __syncthreads();   // single barrier per step
    cur ^= 1;
  }
}

extern "C" void kernel_launch(void* const* d_in, const int* in_sizes, int n_in,
                              void* d_out, int out_size, void* d_ws, size_t ws_size,
                              hipStream_t stream)
{
  (void)in_sizes; (void)n_in; (void)out_size; (void)ws_size;
  const float* x   = (const float*)d_in[0];
  const float* hx0 = (const float*)d_in[1];
  const float* wih = (const float*)d_in[2];
  const float* bih = (const float*)d_in[3];
  const float* whh = (const float*)d_in[4];
  const float* bhh = (const float*)d_in[5];
  float* out = (float*)d_out;
  unsigned char* ws = (unsigned char*)d_ws;

  hipMemsetAsync(d_ws, 0, 4096, stream);
  hipMemsetAsync(ws + WS_HW, 0, 65536, stream);

  void* args[] = { (void*)&x, (void*)&hx0, (void*)&wih, (void*)&bih,
                   (void*)&whh, (void*)&bhh, (void*)&out, (void*)&ws };
  hipLaunchCooperativeKernel(reinterpret_cast<void*>(fsu_kernel),
                             dim3(NBLK), dim3(NTHR), args, 0, stream);
}

// Round 10
// 765.979 us; speedup vs baseline: 1.8483x; 1.8483x over previous
//
#include <hip/hip_runtime.h>

// FSU-MGU cell: exact integer reimplementation.
// Gate(b,c,t) = sum_w popc( (bits_w & pos_w) | (~bits_w & neg_w) ) + D'(t,c)
// x-gates (input-static) precomputed for ALL t in setup phase D (chunked,
// LDS-staged -> no register spill), stored packed (u16 lo = i_f+2048, hi =
// i_n+2048) into the x-mask region of the masks buffer (exact-fit reuse).
// Main loop: h-gates only (LDS-staged, double-buffered), ONE barrier/step,
// fence-free tagged-slot h exchange ({tag|data} u64 agent atomics).

#define NBLK 256
#define NTHR 1024

// workspace layout (bytes); [0,4096) and hw region zeroed each call
#define WS_BAR_SUB   0u
#define WS_BAR_MST   1024u
#define WS_BAR_FLG   2048u
#define WS_RNGW   8192u
#define WS_RNGWI  9216u
#define WS_RNGM   10240u
#define WS_SRCB   12288u       // 4096 u16
#define WS_SRCW   20480u       // 4096*1024 u16 (end 8,409,088)
#define WS_XP     8409088u     // 64*128*32 u32 (end 9,457,664)
#define WS_HW     9457664u     // 2 region * 4 bg * 64 jt * 16 u64 = 65,536
#define WS_DT     9523200u     // 64*4096 i32 (end 10,571,776)
#define WS_MASKS  10571776u    // 64*4096*32 u64 (end 77,680,640)
// xg(t) overwrites cols [0,2048) of t-slab: 131072 u32 per slab, exact fit.

struct SRng {
  unsigned mt[3][624];
  unsigned yb[3][624];
  unsigned draws[3][1248];
  int perm[3][256];
};
struct SC {
  unsigned short rows[16][1028];
  int rngw[64];
  int rngwi[64];
};
struct SD {
  unsigned xst[32*32];                 // staged x rows (broadcast reads)
  unsigned xgacc[32*1024];             // xg staging (LDS, not regs!) 128 KB
};
struct SL {
  unsigned long long hmask[2][32*34];  // h-gate masks, double-buffered
  unsigned short hrow16[2][32*68];     // h bits u16[row][jt'], double-buffered
  int rngm[16];
};
union SU { SRng r; SC c; SD d; SL l; };

__device__ __forceinline__ unsigned mt_temper(unsigned y){
  y ^= y >> 11;
  y ^= (y << 7)  & 0x9d2c5680u;
  y ^= (y << 15) & 0xefc60000u;
  y ^= y >> 18;
  return y;
}

__device__ void mt_regen_serial(unsigned* mt){
  for (int i = 0; i < 624; i++){
    unsigned y = (mt[i] & 0x80000000u) | (mt[(i+1)%624] & 0x7fffffffu);
    mt[i] = mt[(i+397)%624] ^ (y >> 1) ^ ((y & 1u) ? 0x9908b0dfu : 0u);
  }
}

// numpy legacy RandomState: init_genrand seeding + Fisher-Yates with masked rejection.
__device__ void rng_gen(SU* sm, int* rngw, int* rngwi, int* rngm){
  const int tid = threadIdx.x;
  const int wv = tid >> 6, lane = tid & 63;
  const bool act = (wv < 3);
  if (act && lane == 0){
    unsigned* mt = sm->r.mt[wv];
    mt[0] = (unsigned)wv;  // seeds 0,1,2
    for (int i = 1; i < 624; i++)
      mt[i] = 1812433253u * (mt[i-1] ^ (mt[i-1] >> 30)) + (unsigned)i;
  }
  __syncthreads();
  for (int r = 0; r < 2; r++){
    if (act){
      unsigned* mt = sm->r.mt[wv]; unsigned* yb = sm->r.yb[wv];
      for (int i = lane; i < 623; i += 64)
        yb[i] = (mt[i] & 0x80000000u) | (mt[i+1] & 0x7fffffffu);
    }
    __syncthreads();
    if (act){
      unsigned* mt = sm->r.mt[wv]; unsigned* yb = sm->r.yb[wv];
      for (int i = lane; i < 227; i += 64){
        unsigned y = yb[i];
        mt[i] = mt[i+397] ^ (y >> 1) ^ ((y & 1u) ? 0x9908b0dfu : 0u);
      }
    }
    __syncthreads();
    if (act){
      unsigned* mt = sm->r.mt[wv]; unsigned* yb = sm->r.yb[wv];
      for (int i = 227 + lane; i < 454; i += 64){
        unsigned y = yb[i];
        mt[i] = mt[i-227] ^ (y >> 1) ^ ((y & 1u) ? 0x9908b0dfu : 0u);
      }
    }
    __syncthreads();
    if (act){
      unsigned* mt = sm->r.mt[wv]; unsigned* yb = sm->r.yb[wv];
      for (int i = 454 + lane; i < 624; i += 64){
        unsigned y = (i < 623) ? yb[i]
                   : ((mt[623] & 0x80000000u) | (mt[0] & 0x7fffffffu));
        mt[i] = mt[i-227] ^ (y >> 1) ^ ((y & 1u) ? 0x9908b0dfu : 0u);
      }
    }
    __syncthreads();
    if (act){
      unsigned* mt = sm->r.mt[wv];
      for (int i = lane; i < 624; i += 64)
        sm->r.draws[wv][r*624 + i] = mt_temper(mt[i]);
    }
    __syncthreads();
  }
  if (act && lane == 0){
    const int n = (wv == 2) ? 16 : 256;
    int* perm = sm->r.perm[wv];
    for (int i = 0; i < n; i++) perm[i] = i;
    int dp = 0, spos = 624;
    unsigned* mt = sm->r.mt[wv];
    for (int i = n - 1; i > 0; i--){
      unsigned mask = (unsigned)i;
      mask |= mask >> 1; mask |= mask >> 2; mask |= mask >> 4;
      mask |= mask >> 8; mask |= mask >> 16;
      unsigned v;
      do {
        unsigned d;
        if (dp < 1248) d = sm->r.draws[wv][dp++];
        else {
          if (spos >= 624){ mt_regen_serial(mt); spos = 0; }
          d = mt_temper(mt[spos++]);
        }
        v = d & mask;
      } while (v > (unsigned)i);
      int tmp = perm[i]; perm[i] = perm[v]; perm[v] = tmp;
    }
    int* dst = (wv == 0) ? rngw : (wv == 1) ? rngwi : rngm;
    for (int i = 0; i < n; i++) dst[i] = perm[i];
  }
}

// full-grid barrier WITH fences — setup phases only
__device__ __forceinline__ void gbar_full(unsigned char* ws, unsigned ep){
  __syncthreads();
  if (threadIdx.x == 0){
    __threadfence();
    unsigned* sub = (unsigned*)(ws + WS_BAR_SUB + (blockIdx.x & 7)*128);
    unsigned old = atomicAdd(sub, 1u);
    if (old == ep*32u - 1u){
      unsigned* mst = (unsigned*)(ws + WS_BAR_MST);
      unsigned mo = atomicAdd(mst, 1u);
      if (mo == ep*8u - 1u){
        for (int i = 0; i < 8; i++)
          __hip_atomic_store((unsigned*)(ws + WS_BAR_FLG + i*128), ep,
                             __ATOMIC_RELAXED, __HIP_MEMORY_SCOPE_AGENT);
      }
    }
    const unsigned* fl = (const unsigned*)(ws + WS_BAR_FLG + (blockIdx.x & 7)*128);
    while (__hip_atomic_load(fl, __ATOMIC_RELAXED, __HIP_MEMORY_SCOPE_AGENT) < ep)
      __builtin_amdgcn_s_sleep(8);
  }
  __syncthreads();
  __threadfence();
}

__device__ __forceinline__ int clampi(int v){
  v = v < -512 ? -512 : v;
  v = v >  512 ?  512 : v;
  return v;
}

// (x & p) | (~x & n)  ->  v_bfi_b32
__device__ __forceinline__ unsigned bfi(unsigned x, unsigned p, unsigned n){
  return (x & p) | (~x & n);
}

__global__ void __launch_bounds__(NTHR, 4)
fsu_kernel(const float* __restrict__ x, const float* __restrict__ hx0,
           const float* __restrict__ wih, const float* __restrict__ bih,
           const float* __restrict__ whh, const float* __restrict__ bhh,
           float* __restrict__ out, unsigned char* __restrict__ ws)
{
  __shared__ SU sm;
  const int tid = threadIdx.x;
  const int bid = blockIdx.x;

  int* rngw  = (int*)(ws + WS_RNGW);
  int* rngwi = (int*)(ws + WS_RNGWI);
  int* rngm  = (int*)(ws + WS_RNGM);
  unsigned short* srcb = (unsigned short*)(ws + WS_SRCB);
  unsigned short* srcw = (unsigned short*)(ws + WS_SRCW);
  unsigned* xp   = (unsigned*)(ws + WS_XP);
  unsigned long long* hw = (unsigned long long*)(ws + WS_HW);
  int* Dt = (int*)(ws + WS_DT);
  unsigned long long* masks = (unsigned long long*)(ws + WS_MASKS);
  unsigned* xgpool = (unsigned*)(ws + WS_MASKS);   // u32 view; slab stride 262144

  // ---------- phase 0: RNG tables (block 0) || bit-pack + src build (others)
  if (bid == 0){
    rng_gen(&sm, rngw, rngwi, rngm);
  } else {
    const int gtid = (bid - 1)*NTHR + tid;
    const int lane = tid & 63;
    const int gw = gtid >> 6;
    const int nw = (NBLK-1)*(NTHR/64);
    const int nthr = (NBLK-1)*NTHR;
    for (int ch = gw; ch < 131072; ch += nw){            // x bits
      float v = x[(size_t)ch*64 + lane];
      unsigned long long bal = __ballot(v != 0.0f);
      if ((lane & 31) == 0) xp[ch*2 + (lane >> 5)] = (unsigned)(bal >> lane);
    }
    for (int idx = gtid; idx < 4096; idx += nthr){       // initial h slots (region 0, tag 0)
      int bg2 = idx >> 10, jt2 = (idx >> 4) & 63, rp2 = idx & 15;
      int r0 = bg2*32 + 2*rp2;
      unsigned v = 0;
      for (int j = 0; j < 16; j++){
        v |= (hx0[(size_t)r0*1024 + jt2*16 + j] != 0.0f) ? (1u<<j) : 0u;
        v |= (hx0[(size_t)(r0+1)*1024 + jt2*16 + j] != 0.0f) ? (1u<<(16+j)) : 0u;
      }
      hw[idx] = (unsigned long long)v;  // tag 0; flushed by gbar_full fence
    }
    for (int idx = gtid; idx < 4096*1024; idx += nthr){  // src = round((clip+1)*128)
      int c = idx >> 10, k = idx & 1023;
      float wv2 = (c < 2048) ? wih[(size_t)c*1024 + k] : whh[(size_t)(c - 2048)*1024 + k];
      float cl = fminf(fmaxf(wv2, -1.0f), 1.0f);
      srcw[idx] = (unsigned short)(int)rintf((cl + 1.0f)*0.5f*256.0f);
    }
    for (int c = gtid; c < 4096; c += nthr){
      float bv = (c < 2048) ? bih[c] : bhh[c - 2048];
      float cl = fminf(fmaxf(bv, -1.0f), 1.0f);
      srcb[c] = (unsigned short)(int)rintf((cl + 1.0f)*0.5f*256.0f);
    }
  }
  gbar_full(ws, 1u);

  // ---------- phase C: pos/neg masks + D' constants (popc(neg) folded in)
  {
    const int c0 = bid * 16;
    const unsigned* srcw32 = (const unsigned*)srcw;
    for (int q = tid; q < 16*512; q += NTHR){
      int r = q >> 9, w = q & 511;
      ((unsigned*)&sm.c.rows[r][0])[w] = srcw32[(size_t)(c0 + r)*512 + w];
    }
    if (tid < 64) sm.c.rngw[tid] = rngw[tid];
    if (tid >= 64 && tid < 128) sm.c.rngwi[tid - 64] = rngwi[tid - 64];
    __syncthreads();
    for (int row = tid; row < 1024; row += NTHR){   // (t, local col)
      int t = row >> 4, lc = row & 15, col = c0 + lc;
      int rp = sm.c.rngw[t], ri = sm.c.rngwi[t];
      int hi = rp > ri ? rp : ri;
      int lo1 = (rp < ri ? rp : ri) + 1;
      bool rihi = (ri >= rp);
      const unsigned* srow = (const unsigned*)&sm.c.rows[lc][0];
      unsigned long long* gdst = masks + ((size_t)t*4096 + col)*32;
      int cnti = 0, cntn = 0;
      for (int w = 0; w < 32; w++){
        unsigned pos = 0, neg = 0;
        #pragma unroll
        for (int i2 = 15; i2 >= 0; i2--){
          unsigned v2 = srow[w*16 + i2];
          int vH = (int)(v2 >> 16);
          int vL = (int)(v2 & 0xFFFFu);
          pos = (pos << 1) | ((unsigned)(hi - vH) >> 31);   // v > hi
          neg = (neg << 1) | ((unsigned)(vH - lo1) >> 31);  // v <= lo
          pos = (pos << 1) | ((unsigned)(hi - vL) >> 31);
          neg = (neg << 1) | ((unsigned)(vL - lo1) >> 31);
        }
        gdst[w] = (unsigned long long)pos | ((unsigned long long)neg << 32);
        cnti += rihi ? __popc(pos) : (32 - __popc(neg));    // count(src > ri)
        cntn += __popc(neg);
      }
      Dt[t*4096 + col] = 1024 - cnti - cntn + (((int)srcb[col] > rp) ? 1 : 0);
    }
  }
  gbar_full(ws, 2u);

  // ---------- phase D: x-gates for all t; chunked acc[8] -> LDS staging
  {
    const int tD = bid >> 2, bq = bid & 3;
    {
      int bl = tid >> 5, w = tid & 31;
      sm.d.xst[bl*32 + w] = xp[((size_t)tD*128 + bq*32 + bl)*32 + w];
    }
    __syncthreads();
    const int jcol = tid;
    const int dA = Dt[tD*4096 + jcol] + 2048;          // gate i_f col
    const int dB = Dt[tD*4096 + 1024 + jcol] + 2048;   // gate i_n col
    const unsigned dpack = (unsigned)dA | ((unsigned)dB << 16);
    const uint4* mA = (const uint4*)(masks + ((size_t)tD*4096 + jcol)*32);
    const uint4* mB = (const uint4*)(masks + ((size_t)tD*4096 + 1024 + jcol)*32);
    for (int ch = 0; ch < 4; ch++){
      unsigned acc[8];
      #pragma unroll
      for (int b = 0; b < 8; b++) acc[b] = 0;
      #pragma unroll
      for (int c = 0; c < 4; c++){
        uint4 a0 = mA[c*4+0], a1 = mA[c*4+1], a2 = mA[c*4+2], a3 = mA[c*4+3];
        uint4 g0 = mB[c*4+0], g1 = mB[c*4+1], g2 = mB[c*4+2], g3 = mB[c*4+3];
        #pragma unroll
        for (int b = 0; b < 8; b++){
          const uint4* xv = (const uint4*)&sm.d.xst[(ch*8 + b)*32 + c*8];
          uint4 x0 = xv[0], x1 = xv[1];
          unsigned sA =
              __popc(bfi(x0.x, a0.x, a0.y)) + __popc(bfi(x0.y, a0.z, a0.w)) +
              __popc(bfi(x0.z, a1.x, a1.y)) + __popc(bfi(x0.w, a1.z, a1.w)) +
              __popc(bfi(x1.x, a2.x, a2.y)) + __popc(bfi(x1.y, a2.z, a2.w)) +
              __popc(bfi(x1.z, a3.x, a3.y)) + __popc(bfi(x1.w, a3.z, a3.w));
          unsigned sB =
              __popc(bfi(x0.x, g0.x, g0.y)) + __popc(bfi(x0.y, g0.z, g0.w)) +
              __popc(bfi(x0.z, g1.x, g1.y)) + __popc(bfi(x0.w, g1.z, g1.w)) +
              __popc(bfi(x1.x, g2.x, g2.y)) + __popc(bfi(x1.y, g2.z, g2.w)) +
              __popc(bfi(x1.z, g3.x, g3.y)) + __popc(bfi(x1.w, g3.z, g3.w));
          acc[b] += sA + (sB << 16);
        }
      }
      #pragma unroll
      for (int b = 0; b < 8; b++)
        sm.d.xgacc[(ch*8 + b)*1024 + jcol] = acc[b] + dpack;
    }
    __syncthreads();      // all this block's mask reads + LDS staging complete
    gbar_full(ws, 3u);    // grid-wide: all x-mask reads done everywhere
    unsigned* xgst = xgpool + (size_t)tD*262144;
    #pragma unroll
    for (int i = 0; i < 32; i++){
      int q = tid + i*NTHR;
      int b = q >> 10, j = q & 1023;
      xgst[(size_t)(bq*32 + b)*1024 + j] = sm.d.xgacc[b*1024 + j];
    }
  }
  gbar_full(ws, 4u);

  // ---------- main recurrence
  const int jt = bid & 63, bg = bid >> 6;
  const int j0 = jt * 16, b0 = bg * 32;
  const int kh  = (tid >> 5) & 1;
  const int o   = ((tid >> 6) << 5) + (tid & 31);   // 0..511
  const int b_l = o >> 4, j_l = o & 15;
  const int bglob = b0 + b_l;
  const int w2lo = kh << 3;
  const int jcol = j0 + j_l;

  int hcur = (hx0[(size_t)bglob*1024 + jcol] != 0.0f) ? 1 : 0;
  int A1=0,A2=0,A3=0,A4=0,A5=0,A6=0;
  unsigned sr1=10u, sr2=10u, sr3=10u;
  int i1p=0,i1i=0,i2p=0,i2i=0,i3p=0,i3i=0;

  if (tid < 16) sm.l.rngm[tid] = rngm[tid];

  const unsigned* msrc = (const unsigned*)masks;
  int cur = 0;
  unsigned mreg[2];
  unsigned xg_cur, xg_nxt;
  int dhf, dhn, dh_nf, dh_nn;

  // ---- prime: stage t=0 hmask, initial h, xg/dh for t=0,1, mreg t=1
  {
    unsigned* mbuf = (unsigned*)sm.l.hmask[0];
    #pragma unroll
    for (int i = 0; i < 2; i++){
      int q = tid + i*NTHR;
      int r = q >> 6, qq = q & 63;
      int c = 2048 + (r >> 4)*1024 + j0 + (r & 15);
      mbuf[r*68 + qq] = msrc[((size_t)0*4096 + c)*64 + qq];
    }
    {
      unsigned long long v = __hip_atomic_load(&hw[(size_t)bg*1024 + tid],
                                               __ATOMIC_RELAXED,
                                               __HIP_MEMORY_SCOPE_AGENT);
      int jt_ = tid >> 4, rp_ = tid & 15;
      unsigned data = (unsigned)v;
      sm.l.hrow16[0][(2*rp_)*68 + jt_]   = (unsigned short)(data & 0xFFFFu);
      sm.l.hrow16[0][(2*rp_+1)*68 + jt_] = (unsigned short)(data >> 16);
    }
    xg_cur = xgpool[(size_t)0*262144 + (size_t)bglob*1024 + jcol];
    xg_nxt = xgpool[(size_t)1*262144 + (size_t)bglob*1024 + jcol];
    dhf   = Dt[0*4096 + 2048 + jcol];
    dhn   = Dt[0*4096 + 3072 + jcol];
    dh_nf = Dt[1*4096 + 2048 + jcol];
    dh_nn = Dt[1*4096 + 3072 + jcol];
    #pragma unroll
    for (int i = 0; i < 2; i++){
      int q = tid + i*NTHR;
      int r = q >> 6, qq = q & 63;
      int c = 2048 + (r >> 4)*1024 + j0 + (r & 15);
      mreg[i] = msrc[((size_t)1*4096 + c)*64 + qq];
    }
    __syncthreads();
  }

  for (int t = 0; t < 64; t++){
    const int par = t & 1;

    // ---- h-gate popc (half-K, bfi form) + wave-local combine
    int s2=0, s3=0;
    {
      const uint2* hrow = (const uint2*)&sm.l.hrow16[cur][b_l*68];
      const ulonglong2* m2p = (const ulonglong2*)&sm.l.hmask[cur][(0  + j_l)*34];
      const ulonglong2* m3p = (const ulonglong2*)&sm.l.hmask[cur][(16 + j_l)*34];
      #pragma unroll
      for (int w2i = 0; w2i < 8; w2i++){
        int w2 = w2lo + w2i;
        uint2 hv = hrow[w2];
        ulonglong2 c2 = m2p[w2];
        s2 += __popc(bfi(hv.x, (unsigned)c2.x, (unsigned)(c2.x >> 32)));
        s2 += __popc(bfi(hv.y, (unsigned)c2.y, (unsigned)(c2.y >> 32)));
        ulonglong2 d = m3p[w2];
        s3 += __popc(bfi(hv.x, (unsigned)d.x, (unsigned)(d.x >> 32)));
        s3 += __popc(bfi(hv.y, (unsigned)d.y, (unsigned)(d.y >> 32)));
      }
    }
    s2 += __shfl_xor(s2, 32);
    s3 += __shfl_xor(s3, 32);
    const int g_hf = dhf + s2;
    const int g_hn = dhn + s3;
    const int xgf = (int)(xg_cur & 0xFFFFu) - 2048;
    const int xgn = (int)(xg_cur >> 16) - 2048;

    // ---- FSU elementwise chain (exact, 2x-scaled ints; dup on l, l^32)
    int s1v = xgf + g_hf;
    A1 = clampi(A1 + 2*s1v - 2049);
    int fg_in = (A1 >= 2); A1 -= fg_in << 1;
    A2 = clampi(A2 + ((fg_in + 1) << 1));
    int fg = (A2 >= 4); A2 -= fg << 2;
    A3 = clampi(A3 + (g_hn << 1) - 1024);
    int hnb = (A3 >= 2); A3 -= hnb << 1;

    sr1 = ((sr1 >> 1) | ((unsigned)hnb << 3)) & 0xFu;
    int ng_prod;
    {
      int cv = __popc(sr1) << 2;
      int bp = cv > sm.l.rngm[i1p & 15];
      int bi = cv > sm.l.rngm[i1i & 15];
      ng_prod = fg ? bp : (1 - bi);
      i1p += fg; i1i += 1 - fg;
    }
    A4 = clampi(A4 + (xgn << 1) - 1024);
    int inb = (A4 >= 2); A4 -= inb << 1;
    A5 = clampi(A5 + ((inb + ng_prod) << 1) - 1);
    int ng = (A5 >= 2); A5 -= ng << 1;

    sr2 = ((sr2 >> 1) | ((unsigned)ng << 3)) & 0xFu;
    int fgi;
    {
      int cv = __popc(sr2) << 2;
      int bp = cv > sm.l.rngm[i2p & 15];
      int bi = cv > sm.l.rngm[i2i & 15];
      fgi = (1 - fg) ? bp : (1 - bi);
      i2p += 1 - fg; i2i += fg;
    }
    sr3 = ((sr3 >> 1) | ((unsigned)hcur << 3)) & 0xFu;
    int fgp;
    {
      int cv = __popc(sr3) << 2;
      int bp = cv > sm.l.rngm[i3p & 15];
      int bi = cv > sm.l.rngm[i3i & 15];
      fgp = fg ? bp : (1 - bi);
      i3p += fg; i3i += 1 - fg;
    }
    A6 = clampi(A6 + ((ng + fgi + fgp) << 1) - 2);
    int hy = (A6 >= 2); A6 -= hy << 1;
    hcur = hy;

    if (t < 63){
      unsigned long long bal = __ballot(hy);
      if ((tid & 63) == 0){
        unsigned data = (unsigned)bal;
        unsigned long long val = (unsigned long long)data
                               | ((unsigned long long)(unsigned)(t + 1) << 32);
        __hip_atomic_store(
            &hw[(((size_t)((par ^ 1)*4 + bg))*64 + jt)*16 + (tid >> 6)], val,
            __ATOMIC_RELAXED, __HIP_MEMORY_SCOPE_AGENT);
      }
    }
    if (kh == 0)
      out[(size_t)t*131072 + (size_t)bglob*1024 + jcol] = (float)hy;
    if (t == 63) break;

    // commit prefetched h-mask tile (t+1) into the other buffer
    {
      unsigned* mbuf = (unsigned*)sm.l.hmask[cur ^ 1];
      #pragma unroll
      for (int i = 0; i < 2; i++){
        int q = tid + i*NTHR;
        mbuf[(q >> 6)*68 + (q & 63)] = mreg[i];
      }
    }

    // rotate xg/dh; issue prefetches for t+2
    xg_cur = xg_nxt; dhf = dh_nf; dhn = dh_nn;
    if (t < 62){
      #pragma unroll
      for (int i = 0; i < 2; i++){
        int q = tid + i*NTHR;
        int r = q >> 6, qq = q & 63;
        int c = 2048 + (r >> 4)*1024 + j0 + (r & 15);
        mreg[i] = msrc[((size_t)(t+2)*4096 + c)*64 + qq];
      }
      xg_nxt = xgpool[(size_t)(t+2)*262144 + (size_t)bglob*1024 + jcol];
      dh_nf = Dt[(t+2)*4096 + 2048 + jcol];
      dh_nn = Dt[(t+2)*4096 + 3072 + jcol];
    }

    // pull h(t+1): one tagged slot per thread, tag-spin
    {
      const unsigned ep = (unsigned)(t + 1);
      const unsigned long long* slot =
          &hw[((size_t)((par ^ 1)*4 + bg))*1024 + tid];
      unsigned long long v = __hip_atomic_load(slot, __ATOMIC_RELAXED,
                                               __HIP_MEMORY_SCOPE_AGENT);
      while ((unsigned)(v >> 32) < ep){
        __builtin_amdgcn_s_sleep(2);
        v = __hip_atomic_load(slot, __ATOMIC_RELAXED,
                              __HIP_MEMORY_SCOPE_AGENT);
      }
      int jt_ = tid >> 4, rp_ = tid & 15;
      unsigned data = (unsigned)v;
      sm.l.hrow16[cur ^ 1][(2*rp_)*68 + jt_]   = (unsigned short)(data & 0xFFFFu);
      sm.l.hrow16[cur ^ 1][(2*rp_+1)*68 + jt_] = (unsigned short)(data >> 16);
    }
    __syncthreads();   // single barrier per step
    cur ^= 1;
  }
}

extern "C" void kernel_launch(void* const* d_in, const int* in_sizes, int n_in,
                              void* d_out, int out_size, void* d_ws, size_t ws_size,
                              hipStream_t stream)
{
  (void)in_sizes; (void)n_in; (void)out_size; (void)ws_size;
  const float* x   = (const float*)d_in[0];
  const float* hx0 = (const float*)d_in[1];
  const float* wih = (const float*)d_in[2];
  const float* bih = (const float*)d_in[3];
  const float* whh = (const float*)d_in[4];
  const float* bhh = (const float*)d_in[5];
  float* out = (float*)d_out;
  unsigned char* ws = (unsigned char*)d_ws;

  hipMemsetAsync(d_ws, 0, 4096, stream);
  hipMemsetAsync(ws + WS_HW, 0, 65536, stream);

  void* args[] = { (void*)&x, (void*)&hx0, (void*)&wih, (void*)&bih,
                   (void*)&whh, (void*)&bhh, (void*)&out, (void*)&ws };
  hipLaunchCooperativeKernel(reinterpret_cast<void*>(fsu_kernel),
                             dim3(NBLK), dim3(NTHR), args, 0, stream);
}

// Round 11
// 743.577 us; speedup vs baseline: 1.9040x; 1.0301x over previous
//
#include <hip/hip_runtime.h>

// FSU-MGU cell: exact integer reimplementation.
// Gate(b,c,t) = sum_w popc( (bits_w & pos_w) | (~bits_w & neg_w) ) + D'(t,c)
// x-gates (input-static) precomputed for ALL t in setup phase D. Phase C
// stores x-masks (cols<2048, consumed only by phase D) TRANSPOSED [t][w][col]
// so phase D reads are lane-coalesced; h-masks stay [t][col][w] for the main
// loop. Phase D: single pass, acc[32] in registers (launch_bounds grants 128
// VGPRs), results overwrite the x-mask region (exact fit). Main loop: h-gates
// only (LDS, double-buffered), ONE barrier/step, fence-free tagged-slot h
// exchange ({tag|data} u64 agent atomics).

#define NBLK 256
#define NTHR 1024

// workspace layout (bytes); [0,4096) and hw region zeroed each call
#define WS_BAR_SUB   0u
#define WS_BAR_MST   1024u
#define WS_BAR_FLG   2048u
#define WS_RNGW   8192u
#define WS_RNGWI  9216u
#define WS_RNGM   10240u
#define WS_SRCB   12288u       // 4096 u16
#define WS_SRCW   20480u       // 4096*1024 u16 (end 8,409,088)
#define WS_XP     8409088u     // 64*128*32 u32 (end 9,457,664)
#define WS_HW     9457664u     // 2 region * 4 bg * 64 jt * 16 u64 = 65,536
#define WS_DT     9523200u     // 64*4096 i32 (end 10,571,776)
#define WS_MASKS  10571776u    // 64*4096*32 u64 (end 77,680,640)
// t-slab = 131072 u64. x-region = first 65536 u64 of each slab:
//   phase C writes transposed x-masks [w][col] there; phase D overwrites it
//   with xg(t) (131072 u32 = 65536 u64, exact fit). h-masks (col>=2048) at
//   slab offset >= 65536 u64, untouched.

struct SRng {
  unsigned mt[3][624];
  unsigned yb[3][624];
  unsigned draws[3][1248];
  int perm[3][256];
};
struct SC {
  unsigned short rows[16][1028];
  int rngw[64];
  int rngwi[64];
};
struct SD {
  unsigned xst[32*32];                 // staged x rows (broadcast reads)
};
struct SL {
  unsigned long long hmask[2][32*34];  // h-gate masks, double-buffered
  unsigned short hrow16[2][32*68];     // h bits u16[row][jt'], double-buffered
  int rngm[16];
};
union SU { SRng r; SC c; SD d; SL l; };

__device__ __forceinline__ unsigned mt_temper(unsigned y){
  y ^= y >> 11;
  y ^= (y << 7)  & 0x9d2c5680u;
  y ^= (y << 15) & 0xefc60000u;
  y ^= y >> 18;
  return y;
}

__device__ void mt_regen_serial(unsigned* mt){
  for (int i = 0; i < 624; i++){
    unsigned y = (mt[i] & 0x80000000u) | (mt[(i+1)%624] & 0x7fffffffu);
    mt[i] = mt[(i+397)%624] ^ (y >> 1) ^ ((y & 1u) ? 0x9908b0dfu : 0u);
  }
}

// numpy legacy RandomState: init_genrand seeding + Fisher-Yates with masked rejection.
__device__ void rng_gen(SU* sm, int* rngw, int* rngwi, int* rngm){
  const int tid = threadIdx.x;
  const int wv = tid >> 6, lane = tid & 63;
  const bool act = (wv < 3);
  if (act && lane == 0){
    unsigned* mt = sm->r.mt[wv];
    mt[0] = (unsigned)wv;  // seeds 0,1,2
    for (int i = 1; i < 624; i++)
      mt[i] = 1812433253u * (mt[i-1] ^ (mt[i-1] >> 30)) + (unsigned)i;
  }
  __syncthreads();
  for (int r = 0; r < 2; r++){
    if (act){
      unsigned* mt = sm->r.mt[wv]; unsigned* yb = sm->r.yb[wv];
      for (int i = lane; i < 623; i += 64)
        yb[i] = (mt[i] & 0x80000000u) | (mt[i+1] & 0x7fffffffu);
    }
    __syncthreads();
    if (act){
      unsigned* mt = sm->r.mt[wv]; unsigned* yb = sm->r.yb[wv];
      for (int i = lane; i < 227; i += 64){
        unsigned y = yb[i];
        mt[i] = mt[i+397] ^ (y >> 1) ^ ((y & 1u) ? 0x9908b0dfu : 0u);
      }
    }
    __syncthreads();
    if (act){
      unsigned* mt = sm->r.mt[wv]; unsigned* yb = sm->r.yb[wv];
      for (int i = 227 + lane; i < 454; i += 64){
        unsigned y = yb[i];
        mt[i] = mt[i-227] ^ (y >> 1) ^ ((y & 1u) ? 0x9908b0dfu : 0u);
      }
    }
    __syncthreads();
    if (act){
      unsigned* mt = sm->r.mt[wv]; unsigned* yb = sm->r.yb[wv];
      for (int i = 454 + lane; i < 624; i += 64){
        unsigned y = (i < 623) ? yb[i]
                   : ((mt[623] & 0x80000000u) | (mt[0] & 0x7fffffffu));
        mt[i] = mt[i-227] ^ (y >> 1) ^ ((y & 1u) ? 0x9908b0dfu : 0u);
      }
    }
    __syncthreads();
    if (act){
      unsigned* mt = sm->r.mt[wv];
      for (int i = lane; i < 624; i += 64)
        sm->r.draws[wv][r*624 + i] = mt_temper(mt[i]);
    }
    __syncthreads();
  }
  if (act && lane == 0){
    const int n = (wv == 2) ? 16 : 256;
    int* perm = sm->r.perm[wv];
    for (int i = 0; i < n; i++) perm[i] = i;
    int dp = 0, spos = 624;
    unsigned* mt = sm->r.mt[wv];
    for (int i = n - 1; i > 0; i--){
      unsigned mask = (unsigned)i;
      mask |= mask >> 1; mask |= mask >> 2; mask |= mask >> 4;
      mask |= mask >> 8; mask |= mask >> 16;
      unsigned v;
      do {
        unsigned d;
        if (dp < 1248) d = sm->r.draws[wv][dp++];
        else {
          if (spos >= 624){ mt_regen_serial(mt); spos = 0; }
          d = mt_temper(mt[spos++]);
        }
        v = d & mask;
      } while (v > (unsigned)i);
      int tmp = perm[i]; perm[i] = perm[v]; perm[v] = tmp;
    }
    int* dst = (wv == 0) ? rngw : (wv == 1) ? rngwi : rngm;
    for (int i = 0; i < n; i++) dst[i] = perm[i];
  }
}

// full-grid barrier WITH fences — setup phases only
__device__ __forceinline__ void gbar_full(unsigned char* ws, unsigned ep){
  __syncthreads();
  if (threadIdx.x == 0){
    __threadfence();
    unsigned* sub = (unsigned*)(ws + WS_BAR_SUB + (blockIdx.x & 7)*128);
    unsigned old = atomicAdd(sub, 1u);
    if (old == ep*32u - 1u){
      unsigned* mst = (unsigned*)(ws + WS_BAR_MST);
      unsigned mo = atomicAdd(mst, 1u);
      if (mo == ep*8u - 1u){
        for (int i = 0; i < 8; i++)
          __hip_atomic_store((unsigned*)(ws + WS_BAR_FLG + i*128), ep,
                             __ATOMIC_RELAXED, __HIP_MEMORY_SCOPE_AGENT);
      }
    }
    const unsigned* fl = (const unsigned*)(ws + WS_BAR_FLG + (blockIdx.x & 7)*128);
    while (__hip_atomic_load(fl, __ATOMIC_RELAXED, __HIP_MEMORY_SCOPE_AGENT) < ep)
      __builtin_amdgcn_s_sleep(8);
  }
  __syncthreads();
  __threadfence();
}

__device__ __forceinline__ int clampi(int v){
  v = v < -512 ? -512 : v;
  v = v >  512 ?  512 : v;
  return v;
}

// (x & p) | (~x & n)  ->  v_bfi_b32
__device__ __forceinline__ unsigned bfi(unsigned x, unsigned p, unsigned n){
  return (x & p) | (~x & n);
}

__global__ void __launch_bounds__(NTHR, 4)
fsu_kernel(const float* __restrict__ x, const float* __restrict__ hx0,
           const float* __restrict__ wih, const float* __restrict__ bih,
           const float* __restrict__ whh, const float* __restrict__ bhh,
           float* __restrict__ out, unsigned char* __restrict__ ws)
{
  __shared__ SU sm;
  const int tid = threadIdx.x;
  const int bid = blockIdx.x;

  int* rngw  = (int*)(ws + WS_RNGW);
  int* rngwi = (int*)(ws + WS_RNGWI);
  int* rngm  = (int*)(ws + WS_RNGM);
  unsigned short* srcb = (unsigned short*)(ws + WS_SRCB);
  unsigned short* srcw = (unsigned short*)(ws + WS_SRCW);
  unsigned* xp   = (unsigned*)(ws + WS_XP);
  unsigned long long* hw = (unsigned long long*)(ws + WS_HW);
  int* Dt = (int*)(ws + WS_DT);
  unsigned long long* masks = (unsigned long long*)(ws + WS_MASKS);
  unsigned* xgpool = (unsigned*)(ws + WS_MASKS);   // u32 view; slab stride 262144

  // ---------- phase 0: RNG tables (block 0) || bit-pack + src build (others)
  if (bid == 0){
    rng_gen(&sm, rngw, rngwi, rngm);
  } else {
    const int gtid = (bid - 1)*NTHR + tid;
    const int lane = tid & 63;
    const int gw = gtid >> 6;
    const int nw = (NBLK-1)*(NTHR/64);
    const int nthr = (NBLK-1)*NTHR;
    for (int ch = gw; ch < 131072; ch += nw){            // x bits
      float v = x[(size_t)ch*64 + lane];
      unsigned long long bal = __ballot(v != 0.0f);
      if ((lane & 31) == 0) xp[ch*2 + (lane >> 5)] = (unsigned)(bal >> lane);
    }
    for (int idx = gtid; idx < 4096; idx += nthr){       // initial h slots (region 0, tag 0)
      int bg2 = idx >> 10, jt2 = (idx >> 4) & 63, rp2 = idx & 15;
      int r0 = bg2*32 + 2*rp2;
      unsigned v = 0;
      for (int j = 0; j < 16; j++){
        v |= (hx0[(size_t)r0*1024 + jt2*16 + j] != 0.0f) ? (1u<<j) : 0u;
        v |= (hx0[(size_t)(r0+1)*1024 + jt2*16 + j] != 0.0f) ? (1u<<(16+j)) : 0u;
      }
      hw[idx] = (unsigned long long)v;  // tag 0; flushed by gbar_full fence
    }
    for (int idx = gtid; idx < 4096*1024; idx += nthr){  // src = round((clip+1)*128)
      int c = idx >> 10, k = idx & 1023;
      float wv2 = (c < 2048) ? wih[(size_t)c*1024 + k] : whh[(size_t)(c - 2048)*1024 + k];
      float cl = fminf(fmaxf(wv2, -1.0f), 1.0f);
      srcw[idx] = (unsigned short)(int)rintf((cl + 1.0f)*0.5f*256.0f);
    }
    for (int c = gtid; c < 4096; c += nthr){
      float bv = (c < 2048) ? bih[c] : bhh[c - 2048];
      float cl = fminf(fmaxf(bv, -1.0f), 1.0f);
      srcb[c] = (unsigned short)(int)rintf((cl + 1.0f)*0.5f*256.0f);
    }
  }
  gbar_full(ws, 1u);

  // ---------- phase C: pos/neg masks + D' constants (popc(neg) folded in)
  // cols < 2048 (x-gates): stored TRANSPOSED [t][w][col] for phase D.
  // cols >= 2048 (h-gates): stored [t][col][w] for the main loop.
  {
    const int c0 = bid * 16;
    const unsigned* srcw32 = (const unsigned*)srcw;
    for (int q = tid; q < 16*512; q += NTHR){
      int r = q >> 9, w = q & 511;
      ((unsigned*)&sm.c.rows[r][0])[w] = srcw32[(size_t)(c0 + r)*512 + w];
    }
    if (tid < 64) sm.c.rngw[tid] = rngw[tid];
    if (tid >= 64 && tid < 128) sm.c.rngwi[tid - 64] = rngwi[tid - 64];
    __syncthreads();
    const bool xside = (c0 < 2048);
    for (int row = tid; row < 1024; row += NTHR){   // (t, local col)
      int t = row >> 4, lc = row & 15, col = c0 + lc;
      int rp = sm.c.rngw[t], ri = sm.c.rngwi[t];
      int hi = rp > ri ? rp : ri;
      int lo1 = (rp < ri ? rp : ri) + 1;
      bool rihi = (ri >= rp);
      const unsigned* srow = (const unsigned*)&sm.c.rows[lc][0];
      unsigned long long* slab = masks + (size_t)t*131072;
      int cnti = 0, cntn = 0;
      for (int w = 0; w < 32; w++){
        unsigned pos = 0, neg = 0;
        #pragma unroll
        for (int i2 = 15; i2 >= 0; i2--){
          unsigned v2 = srow[w*16 + i2];
          int vH = (int)(v2 >> 16);
          int vL = (int)(v2 & 0xFFFFu);
          pos = (pos << 1) | ((unsigned)(hi - vH) >> 31);   // v > hi
          neg = (neg << 1) | ((unsigned)(vH - lo1) >> 31);  // v <= lo
          pos = (pos << 1) | ((unsigned)(hi - vL) >> 31);
          neg = (neg << 1) | ((unsigned)(vL - lo1) >> 31);
        }
        unsigned long long mval = (unsigned long long)pos
                                | ((unsigned long long)neg << 32);
        if (xside) slab[(size_t)w*2048 + col] = mval;          // transposed
        else       slab[(size_t)col*32 + w] = mval;            // row-major
        cnti += rihi ? __popc(pos) : (32 - __popc(neg));    // count(src > ri)
        cntn += __popc(neg);
      }
      Dt[t*4096 + col] = 1024 - cnti - cntn + (((int)srcb[col] > rp) ? 1 : 0);
    }
  }
  gbar_full(ws, 2u);

  // ---------- phase D: x-gates for all t; coalesced reads, acc[32] in regs
  {
    const int tD = bid >> 2, bq = bid & 3;
    {
      int bl = tid >> 5, w = tid & 31;
      sm.d.xst[bl*32 + w] = xp[((size_t)tD*128 + bq*32 + bl)*32 + w];
    }
    __syncthreads();
    const int jcol = tid;
    const int dA = Dt[tD*4096 + jcol] + 2048;          // gate i_f col
    const int dB = Dt[tD*4096 + 1024 + jcol] + 2048;   // gate i_n col
    const unsigned dpack = (unsigned)dA | ((unsigned)dB << 16);
    const unsigned long long* mtb = masks + (size_t)tD*131072;
    unsigned acc[32];
    #pragma unroll
    for (int b = 0; b < 32; b++) acc[b] = 0;
    for (int w = 0; w < 32; w++){
      unsigned long long a = mtb[(size_t)w*2048 + jcol];         // coalesced
      unsigned long long g = mtb[(size_t)w*2048 + 1024 + jcol];  // coalesced
      unsigned alo = (unsigned)a, ahi = (unsigned)(a >> 32);
      unsigned glo = (unsigned)g, ghi = (unsigned)(g >> 32);
      #pragma unroll
      for (int b = 0; b < 32; b++){
        unsigned xw = sm.d.xst[b*32 + w];   // wave-uniform broadcast
        acc[b] += __popc(bfi(xw, alo, ahi))
                + (__popc(bfi(xw, glo, ghi)) << 16);
      }
    }
    gbar_full(ws, 3u);    // grid-wide: all x-mask reads done everywhere
    unsigned* xgst = xgpool + (size_t)tD*262144;
    #pragma unroll
    for (int b = 0; b < 32; b++)
      xgst[(size_t)(bq*32 + b)*1024 + jcol] = acc[b] + dpack;   // coalesced
  }
  gbar_full(ws, 4u);

  // ---------- main recurrence
  const int jt = bid & 63, bg = bid >> 6;
  const int j0 = jt * 16, b0 = bg * 32;
  const int kh  = (tid >> 5) & 1;
  const int o   = ((tid >> 6) << 5) + (tid & 31);   // 0..511
  const int b_l = o >> 4, j_l = o & 15;
  const int bglob = b0 + b_l;
  const int w2lo = kh << 3;
  const int jcol = j0 + j_l;

  int hcur = (hx0[(size_t)bglob*1024 + jcol] != 0.0f) ? 1 : 0;
  int A1=0,A2=0,A3=0,A4=0,A5=0,A6=0;
  unsigned sr1=10u, sr2=10u, sr3=10u;
  int i1p=0,i1i=0,i2p=0,i2i=0,i3p=0,i3i=0;

  if (tid < 16) sm.l.rngm[tid] = rngm[tid];

  const unsigned* msrc = (const unsigned*)masks;
  int cur = 0;
  unsigned mreg[2];
  unsigned xg_cur, xg_nxt;
  int dhf, dhn, dh_nf, dh_nn;

  // ---- prime: stage t=0 hmask, initial h, xg/dh for t=0,1, mreg t=1
  {
    unsigned* mbuf = (unsigned*)sm.l.hmask[0];
    #pragma unroll
    for (int i = 0; i < 2; i++){
      int q = tid + i*NTHR;
      int r = q >> 6, qq = q & 63;
      int c = 2048 + (r >> 4)*1024 + j0 + (r & 15);
      mbuf[r*68 + qq] = msrc[((size_t)0*4096 + c)*64 + qq];
    }
    {
      unsigned long long v = __hip_atomic_load(&hw[(size_t)bg*1024 + tid],
                                               __ATOMIC_RELAXED,
                                               __HIP_MEMORY_SCOPE_AGENT);
      int jt_ = tid >> 4, rp_ = tid & 15;
      unsigned data = (unsigned)v;
      sm.l.hrow16[0][(2*rp_)*68 + jt_]   = (unsigned short)(data & 0xFFFFu);
      sm.l.hrow16[0][(2*rp_+1)*68 + jt_] = (unsigned short)(data >> 16);
    }
    xg_cur = xgpool[(size_t)0*262144 + (size_t)bglob*1024 + jcol];
    xg_nxt = xgpool[(size_t)1*262144 + (size_t)bglob*1024 + jcol];
    dhf   = Dt[0*4096 + 2048 + jcol];
    dhn   = Dt[0*4096 + 3072 + jcol];
    dh_nf = Dt[1*4096 + 2048 + jcol];
    dh_nn = Dt[1*4096 + 3072 + jcol];
    #pragma unroll
    for (int i = 0; i < 2; i++){
      int q = tid + i*NTHR;
      int r = q >> 6, qq = q & 63;
      int c = 2048 + (r >> 4)*1024 + j0 + (r & 15);
      mreg[i] = msrc[((size_t)1*4096 + c)*64 + qq];
    }
    __syncthreads();
  }

  for (int t = 0; t < 64; t++){
    const int par = t & 1;

    // ---- h-gate popc (half-K, bfi form) + wave-local combine
    int s2=0, s3=0;
    {
      const uint2* hrow = (const uint2*)&sm.l.hrow16[cur][b_l*68];
      const ulonglong2* m2p = (const ulonglong2*)&sm.l.hmask[cur][(0  + j_l)*34];
      const ulonglong2* m3p = (const ulonglong2*)&sm.l.hmask[cur][(16 + j_l)*34];
      #pragma unroll
      for (int w2i = 0; w2i < 8; w2i++){
        int w2 = w2lo + w2i;
        uint2 hv = hrow[w2];
        ulonglong2 c2 = m2p[w2];
        s2 += __popc(bfi(hv.x, (unsigned)c2.x, (unsigned)(c2.x >> 32)));
        s2 += __popc(bfi(hv.y, (unsigned)c2.y, (unsigned)(c2.y >> 32)));
        ulonglong2 d = m3p[w2];
        s3 += __popc(bfi(hv.x, (unsigned)d.x, (unsigned)(d.x >> 32)));
        s3 += __popc(bfi(hv.y, (unsigned)d.y, (unsigned)(d.y >> 32)));
      }
    }
    s2 += __shfl_xor(s2, 32);
    s3 += __shfl_xor(s3, 32);
    const int g_hf = dhf + s2;
    const int g_hn = dhn + s3;
    const int xgf = (int)(xg_cur & 0xFFFFu) - 2048;
    const int xgn = (int)(xg_cur >> 16) - 2048;

    // ---- FSU elementwise chain (exact, 2x-scaled ints; dup on l, l^32)
    int s1v = xgf + g_hf;
    A1 = clampi(A1 + 2*s1v - 2049);
    int fg_in = (A1 >= 2); A1 -= fg_in << 1;
    A2 = clampi(A2 + ((fg_in + 1) << 1));
    int fg = (A2 >= 4); A2 -= fg << 2;
    A3 = clampi(A3 + (g_hn << 1) - 1024);
    int hnb = (A3 >= 2); A3 -= hnb << 1;

    sr1 = ((sr1 >> 1) | ((unsigned)hnb << 3)) & 0xFu;
    int ng_prod;
    {
      int cv = __popc(sr1) << 2;
      int bp = cv > sm.l.rngm[i1p & 15];
      int bi = cv > sm.l.rngm[i1i & 15];
      ng_prod = fg ? bp : (1 - bi);
      i1p += fg; i1i += 1 - fg;
    }
    A4 = clampi(A4 + (xgn << 1) - 1024);
    int inb = (A4 >= 2); A4 -= inb << 1;
    A5 = clampi(A5 + ((inb + ng_prod) << 1) - 1);
    int ng = (A5 >= 2); A5 -= ng << 1;

    sr2 = ((sr2 >> 1) | ((unsigned)ng << 3)) & 0xFu;
    int fgi;
    {
      int cv = __popc(sr2) << 2;
      int bp = cv > sm.l.rngm[i2p & 15];
      int bi = cv > sm.l.rngm[i2i & 15];
      fgi = (1 - fg) ? bp : (1 - bi);
      i2p += 1 - fg; i2i += fg;
    }
    sr3 = ((sr3 >> 1) | ((unsigned)hcur << 3)) & 0xFu;
    int fgp;
    {
      int cv = __popc(sr3) << 2;
      int bp = cv > sm.l.rngm[i3p & 15];
      int bi = cv > sm.l.rngm[i3i & 15];
      fgp = fg ? bp : (1 - bi);
      i3p += fg; i3i += 1 - fg;
    }
    A6 = clampi(A6 + ((ng + fgi + fgp) << 1) - 2);
    int hy = (A6 >= 2); A6 -= hy << 1;
    hcur = hy;

    if (t < 63){
      unsigned long long bal = __ballot(hy);
      if ((tid & 63) == 0){
        unsigned data = (unsigned)bal;
        unsigned long long val = (unsigned long long)data
                               | ((unsigned long long)(unsigned)(t + 1) << 32);
        __hip_atomic_store(
            &hw[(((size_t)((par ^ 1)*4 + bg))*64 + jt)*16 + (tid >> 6)], val,
            __ATOMIC_RELAXED, __HIP_MEMORY_SCOPE_AGENT);
      }
    }
    if (kh == 0)
      out[(size_t)t*131072 + (size_t)bglob*1024 + jcol] = (float)hy;
    if (t == 63) break;

    // commit prefetched h-mask tile (t+1) into the other buffer
    {
      unsigned* mbuf = (unsigned*)sm.l.hmask[cur ^ 1];
      #pragma unroll
      for (int i = 0; i < 2; i++){
        int q = tid + i*NTHR;
        mbuf[(q >> 6)*68 + (q & 63)] = mreg[i];
      }
    }

    // rotate xg/dh; issue prefetches for t+2
    xg_cur = xg_nxt; dhf = dh_nf; dhn = dh_nn;
    if (t < 62){
      #pragma unroll
      for (int i = 0; i < 2; i++){
        int q = tid + i*NTHR;
        int r = q >> 6, qq = q & 63;
        int c = 2048 + (r >> 4)*1024 + j0 + (r & 15);
        mreg[i] = msrc[((size_t)(t+2)*4096 + c)*64 + qq];
      }
      xg_nxt = xgpool[(size_t)(t+2)*262144 + (size_t)bglob*1024 + jcol];
      dh_nf = Dt[(t+2)*4096 + 2048 + jcol];
      dh_nn = Dt[(t+2)*4096 + 3072 + jcol];
    }

    // pull h(t+1): one tagged slot per thread, tag-spin
    {
      const unsigned ep = (unsigned)(t + 1);
      const unsigned long long* slot =
          &hw[((size_t)((par ^ 1)*4 + bg))*1024 + tid];
      unsigned long long v = __hip_atomic_load(slot, __ATOMIC_RELAXED,
                                               __HIP_MEMORY_SCOPE_AGENT);
      while ((unsigned)(v >> 32) < ep){
        __builtin_amdgcn_s_sleep(2);
        v = __hip_atomic_load(slot, __ATOMIC_RELAXED,
                              __HIP_MEMORY_SCOPE_AGENT);
      }
      int jt_ = tid >> 4, rp_ = tid & 15;
      unsigned data = (unsigned)v;
      sm.l.hrow16[cur ^ 1][(2*rp_)*68 + jt_]   = (unsigned short)(data & 0xFFFFu);
      sm.l.hrow16[cur ^ 1][(2*rp_+1)*68 + jt_] = (unsigned short)(data >> 16);
    }
    __syncthreads();   // single barrier per step
    cur ^= 1;
  }
}

extern "C" void kernel_launch(void* const* d_in, const int* in_sizes, int n_in,
                              void* d_out, int out_size, void* d_ws, size_t ws_size,
                              hipStream_t stream)
{
  (void)in_sizes; (void)n_in; (void)out_size; (void)ws_size;
  const float* x   = (const float*)d_in[0];
  const float* hx0 = (const float*)d_in[1];
  const float* wih = (const float*)d_in[2];
  const float* bih = (const float*)d_in[3];
  const float* whh = (const float*)d_in[4];
  const float* bhh = (const float*)d_in[5];
  float* out = (float*)d_out;
  unsigned char* ws = (unsigned char*)d_ws;

  hipMemsetAsync(d_ws, 0, 4096, stream);
  hipMemsetAsync(ws + WS_HW, 0, 65536, stream);

  void* args[] = { (void*)&x, (void*)&hx0, (void*)&wih, (void*)&bih,
                   (void*)&whh, (void*)&bhh, (void*)&out, (void*)&ws };
  hipLaunchCooperativeKernel(reinterpret_cast<void*>(fsu_kernel),
                             dim3(NBLK), dim3(NTHR), args, 0, stream);
}

// Round 12
// 654.499 us; speedup vs baseline: 2.1631x; 1.1361x over previous
//
#include <hip/hip_runtime.h>

// FSU-MGU cell: exact integer reimplementation.
// Gate(b,c,t) = sum_w popc( (bits_w & pos_w) | (~bits_w & neg_w) ) + D'(t,c)
// x-gates precomputed for ALL t in phase D (coalesced transposed reads,
// XCD-local sibling mapping tD=bid&63, acc[32] in regs, unfenced WAR barrier).
// Main loop: h-gates only (LDS double-buffered), Dt table in LDS, ONE
// barrier/step, fence-free tagged-slot h exchange ({tag|data} u64 atomics).

#define NBLK 256
#define NTHR 1024

// workspace layout (bytes); [0,4096) and hw region zeroed each call
#define WS_BAR_SUB   0u
#define WS_BAR_MST   1024u
#define WS_BAR_FLG   2048u
#define WS_RNGW   8192u
#define WS_RNGWI  9216u
#define WS_RNGM   10240u
#define WS_SRCB   12288u       // 4096 u16
#define WS_SRCW   20480u       // 4096*1024 u16 (end 8,409,088)
#define WS_XP     8409088u     // 64*128*32 u32 (end 9,457,664)
#define WS_HW     9457664u     // 2 region * 4 bg * 64 jt * 16 u64 = 65,536
#define WS_DT     9523200u     // 64*4096 i32 (end 10,571,776)
#define WS_MASKS  10571776u    // 64*4096*32 u64 (end 77,680,640)
// t-slab = 131072 u64. x-region = first 65536 u64 of each slab: phase C
// writes transposed x-masks [w][col]; phase D overwrites with xg(t)
// (131072 u32, exact fit). h-masks at slab offset >= 65536 u64.

struct SRng {
  unsigned mt[3][624];
  unsigned yb[3][624];
  unsigned draws[3][1248];
  int perm[3][256];
};
struct SC {
  unsigned short rows[16][1028];
  int rngw[64];
  int rngwi[64];
};
struct SD {
  unsigned xst[32*32];                 // staged x rows (broadcast reads)
};
struct SL {
  unsigned long long hmask[2][32*34];  // h-gate masks, double-buffered
  unsigned short hrow16[2][32*68];     // h bits u16[row][jt'], double-buffered
  int dh2[64*16*2];                    // (dhf,dhn) per (t, j_l) -- 8 KB
  int rngm[16];
};
union SU { SRng r; SC c; SD d; SL l; };

__device__ __forceinline__ unsigned mt_temper(unsigned y){
  y ^= y >> 11;
  y ^= (y << 7)  & 0x9d2c5680u;
  y ^= (y << 15) & 0xefc60000u;
  y ^= y >> 18;
  return y;
}

__device__ void mt_regen_serial(unsigned* mt){
  for (int i = 0; i < 624; i++){
    unsigned y = (mt[i] & 0x80000000u) | (mt[(i+1)%624] & 0x7fffffffu);
    mt[i] = mt[(i+397)%624] ^ (y >> 1) ^ ((y & 1u) ? 0x9908b0dfu : 0u);
  }
}

// numpy legacy RandomState: init_genrand seeding + Fisher-Yates with masked rejection.
__device__ void rng_gen(SU* sm, int* rngw, int* rngwi, int* rngm){
  const int tid = threadIdx.x;
  const int wv = tid >> 6, lane = tid & 63;
  const bool act = (wv < 3);
  if (act && lane == 0){
    unsigned* mt = sm->r.mt[wv];
    mt[0] = (unsigned)wv;  // seeds 0,1,2
    for (int i = 1; i < 624; i++)
      mt[i] = 1812433253u * (mt[i-1] ^ (mt[i-1] >> 30)) + (unsigned)i;
  }
  __syncthreads();
  for (int r = 0; r < 2; r++){
    if (act){
      unsigned* mt = sm->r.mt[wv]; unsigned* yb = sm->r.yb[wv];
      for (int i = lane; i < 623; i += 64)
        yb[i] = (mt[i] & 0x80000000u) | (mt[i+1] & 0x7fffffffu);
    }
    __syncthreads();
    if (act){
      unsigned* mt = sm->r.mt[wv]; unsigned* yb = sm->r.yb[wv];
      for (int i = lane; i < 227; i += 64){
        unsigned y = yb[i];
        mt[i] = mt[i+397] ^ (y >> 1) ^ ((y & 1u) ? 0x9908b0dfu : 0u);
      }
    }
    __syncthreads();
    if (act){
      unsigned* mt = sm->r.mt[wv]; unsigned* yb = sm->r.yb[wv];
      for (int i = 227 + lane; i < 454; i += 64){
        unsigned y = yb[i];
        mt[i] = mt[i-227] ^ (y >> 1) ^ ((y & 1u) ? 0x9908b0dfu : 0u);
      }
    }
    __syncthreads();
    if (act){
      unsigned* mt = sm->r.mt[wv]; unsigned* yb = sm->r.yb[wv];
      for (int i = 454 + lane; i < 624; i += 64){
        unsigned y = (i < 623) ? yb[i]
                   : ((mt[623] & 0x80000000u) | (mt[0] & 0x7fffffffu));
        mt[i] = mt[i-227] ^ (y >> 1) ^ ((y & 1u) ? 0x9908b0dfu : 0u);
      }
    }
    __syncthreads();
    if (act){
      unsigned* mt = sm->r.mt[wv];
      for (int i = lane; i < 624; i += 64)
        sm->r.draws[wv][r*624 + i] = mt_temper(mt[i]);
    }
    __syncthreads();
  }
  if (act && lane == 0){
    const int n = (wv == 2) ? 16 : 256;
    int* perm = sm->r.perm[wv];
    for (int i = 0; i < n; i++) perm[i] = i;
    int dp = 0, spos = 624;
    unsigned* mt = sm->r.mt[wv];
    for (int i = n - 1; i > 0; i--){
      unsigned mask = (unsigned)i;
      mask |= mask >> 1; mask |= mask >> 2; mask |= mask >> 4;
      mask |= mask >> 8; mask |= mask >> 16;
      unsigned v;
      do {
        unsigned d;
        if (dp < 1248) d = sm->r.draws[wv][dp++];
        else {
          if (spos >= 624){ mt_regen_serial(mt); spos = 0; }
          d = mt_temper(mt[spos++]);
        }
        v = d & mask;
      } while (v > (unsigned)i);
      int tmp = perm[i]; perm[i] = perm[v]; perm[v] = tmp;
    }
    int* dst = (wv == 0) ? rngw : (wv == 1) ? rngwi : rngm;
    for (int i = 0; i < n; i++) dst[i] = perm[i];
  }
}

// full-grid barrier WITH fences — publication barriers (setup)
__device__ __forceinline__ void gbar_full(unsigned char* ws, unsigned ep){
  __syncthreads();
  if (threadIdx.x == 0){
    __threadfence();
    unsigned* sub = (unsigned*)(ws + WS_BAR_SUB + (blockIdx.x & 7)*128);
    unsigned old = atomicAdd(sub, 1u);
    if (old == ep*32u - 1u){
      unsigned* mst = (unsigned*)(ws + WS_BAR_MST);
      unsigned mo = atomicAdd(mst, 1u);
      if (mo == ep*8u - 1u){
        for (int i = 0; i < 8; i++)
          __hip_atomic_store((unsigned*)(ws + WS_BAR_FLG + i*128), ep,
                             __ATOMIC_RELAXED, __HIP_MEMORY_SCOPE_AGENT);
      }
    }
    const unsigned* fl = (const unsigned*)(ws + WS_BAR_FLG + (blockIdx.x & 7)*128);
    while (__hip_atomic_load(fl, __ATOMIC_RELAXED, __HIP_MEMORY_SCOPE_AGENT) < ep)
      __builtin_amdgcn_s_sleep(8);
  }
  __syncthreads();
  __threadfence();
}

// full-grid barrier WITHOUT fences — read-completion only (WAR hazards).
// __syncthreads() drains each wave's vmcnt before s_barrier, so arrival
// implies all the block's reads have completed.
__device__ __forceinline__ void gbar_nofence(unsigned char* ws, unsigned ep){
  __syncthreads();
  if (threadIdx.x == 0){
    unsigned* sub = (unsigned*)(ws + WS_BAR_SUB + (blockIdx.x & 7)*128);
    unsigned old = atomicAdd(sub, 1u);
    if (old == ep*32u - 1u){
      unsigned* mst = (unsigned*)(ws + WS_BAR_MST);
      unsigned mo = atomicAdd(mst, 1u);
      if (mo == ep*8u - 1u){
        for (int i = 0; i < 8; i++)
          __hip_atomic_store((unsigned*)(ws + WS_BAR_FLG + i*128), ep,
                             __ATOMIC_RELAXED, __HIP_MEMORY_SCOPE_AGENT);
      }
    }
    const unsigned* fl = (const unsigned*)(ws + WS_BAR_FLG + (blockIdx.x & 7)*128);
    while (__hip_atomic_load(fl, __ATOMIC_RELAXED, __HIP_MEMORY_SCOPE_AGENT) < ep)
      __builtin_amdgcn_s_sleep(8);
  }
  __syncthreads();
}

__device__ __forceinline__ int clampi(int v){
  v = v < -512 ? -512 : v;
  v = v >  512 ?  512 : v;
  return v;
}

// (x & p) | (~x & n)  ->  v_bfi_b32
__device__ __forceinline__ unsigned bfi(unsigned x, unsigned p, unsigned n){
  return (x & p) | (~x & n);
}

__global__ void __launch_bounds__(NTHR, 4)
fsu_kernel(const float* __restrict__ x, const float* __restrict__ hx0,
           const float* __restrict__ wih, const float* __restrict__ bih,
           const float* __restrict__ whh, const float* __restrict__ bhh,
           float* __restrict__ out, unsigned char* __restrict__ ws)
{
  __shared__ SU sm;
  const int tid = threadIdx.x;
  const int bid = blockIdx.x;

  int* rngw  = (int*)(ws + WS_RNGW);
  int* rngwi = (int*)(ws + WS_RNGWI);
  int* rngm  = (int*)(ws + WS_RNGM);
  unsigned short* srcb = (unsigned short*)(ws + WS_SRCB);
  unsigned short* srcw = (unsigned short*)(ws + WS_SRCW);
  unsigned* xp   = (unsigned*)(ws + WS_XP);
  unsigned long long* hw = (unsigned long long*)(ws + WS_HW);
  int* Dt = (int*)(ws + WS_DT);
  unsigned long long* masks = (unsigned long long*)(ws + WS_MASKS);
  unsigned* xgpool = (unsigned*)(ws + WS_MASKS);   // u32 view; slab stride 262144

  // ---------- phase 0: RNG tables (block 0) || bit-pack + src build (others)
  if (bid == 0){
    rng_gen(&sm, rngw, rngwi, rngm);
  } else {
    const int gtid = (bid - 1)*NTHR + tid;
    const int lane = tid & 63;
    const int gw = gtid >> 6;
    const int nw = (NBLK-1)*(NTHR/64);
    const int nthr = (NBLK-1)*NTHR;
    for (int ch = gw; ch < 131072; ch += nw){            // x bits
      float v = x[(size_t)ch*64 + lane];
      unsigned long long bal = __ballot(v != 0.0f);
      if ((lane & 31) == 0) xp[ch*2 + (lane >> 5)] = (unsigned)(bal >> lane);
    }
    for (int idx = gtid; idx < 4096; idx += nthr){       // initial h slots (region 0, tag 0)
      int bg2 = idx >> 10, jt2 = (idx >> 4) & 63, rp2 = idx & 15;
      int r0 = bg2*32 + 2*rp2;
      unsigned v = 0;
      for (int j = 0; j < 16; j++){
        v |= (hx0[(size_t)r0*1024 + jt2*16 + j] != 0.0f) ? (1u<<j) : 0u;
        v |= (hx0[(size_t)(r0+1)*1024 + jt2*16 + j] != 0.0f) ? (1u<<(16+j)) : 0u;
      }
      hw[idx] = (unsigned long long)v;  // tag 0; flushed by gbar_full fence
    }
    for (int idx = gtid; idx < 4096*1024; idx += nthr){  // src = round((clip+1)*128)
      int c = idx >> 10, k = idx & 1023;
      float wv2 = (c < 2048) ? wih[(size_t)c*1024 + k] : whh[(size_t)(c - 2048)*1024 + k];
      float cl = fminf(fmaxf(wv2, -1.0f), 1.0f);
      srcw[idx] = (unsigned short)(int)rintf((cl + 1.0f)*0.5f*256.0f);
    }
    for (int c = gtid; c < 4096; c += nthr){
      float bv = (c < 2048) ? bih[c] : bhh[c - 2048];
      float cl = fminf(fmaxf(bv, -1.0f), 1.0f);
      srcb[c] = (unsigned short)(int)rintf((cl + 1.0f)*0.5f*256.0f);
    }
  }
  gbar_full(ws, 1u);

  // ---------- phase C: pos/neg masks + D' constants (popc(neg) folded in)
  // cols < 2048 (x-gates): stored TRANSPOSED [t][w][col] for phase D.
  // cols >= 2048 (h-gates): stored [t][col][w] for the main loop.
  {
    const int c0 = bid * 16;
    const unsigned* srcw32 = (const unsigned*)srcw;
    for (int q = tid; q < 16*512; q += NTHR){
      int r = q >> 9, w = q & 511;
      ((unsigned*)&sm.c.rows[r][0])[w] = srcw32[(size_t)(c0 + r)*512 + w];
    }
    if (tid < 64) sm.c.rngw[tid] = rngw[tid];
    if (tid >= 64 && tid < 128) sm.c.rngwi[tid - 64] = rngwi[tid - 64];
    __syncthreads();
    const bool xside = (c0 < 2048);
    for (int row = tid; row < 1024; row += NTHR){   // (t, local col)
      int t = row >> 4, lc = row & 15, col = c0 + lc;
      int rp = sm.c.rngw[t], ri = sm.c.rngwi[t];
      int hi = rp > ri ? rp : ri;
      int lo1 = (rp < ri ? rp : ri) + 1;
      bool rihi = (ri >= rp);
      const unsigned* srow = (const unsigned*)&sm.c.rows[lc][0];
      unsigned long long* slab = masks + (size_t)t*131072;
      int cnti = 0, cntn = 0;
      for (int w = 0; w < 32; w++){
        unsigned pos = 0, neg = 0;
        #pragma unroll
        for (int i2 = 15; i2 >= 0; i2--){
          unsigned v2 = srow[w*16 + i2];
          int vH = (int)(v2 >> 16);
          int vL = (int)(v2 & 0xFFFFu);
          pos = (pos << 1) | ((unsigned)(hi - vH) >> 31);   // v > hi
          neg = (neg << 1) | ((unsigned)(vH - lo1) >> 31);  // v <= lo
          pos = (pos << 1) | ((unsigned)(hi - vL) >> 31);
          neg = (neg << 1) | ((unsigned)(vL - lo1) >> 31);
        }
        unsigned long long mval = (unsigned long long)pos
                                | ((unsigned long long)neg << 32);
        if (xside) slab[(size_t)w*2048 + col] = mval;          // transposed
        else       slab[(size_t)col*32 + w] = mval;            // row-major
        cnti += rihi ? __popc(pos) : (32 - __popc(neg));    // count(src > ri)
        cntn += __popc(neg);
      }
      Dt[t*4096 + col] = 1024 - cnti - cntn + (((int)srcb[col] > rp) ? 1 : 0);
    }
  }
  gbar_full(ws, 2u);

  // ---------- phase D: x-gates for all t; coalesced reads, acc[32] in regs.
  // tD = bid & 63: the 4 bq-siblings share an XCD (bid%8 law) -> x-mask slab
  // read once per L2, not 4x through L3.
  {
    const int tD = bid & 63, bq = bid >> 6;
    {
      int bl = tid >> 5, w = tid & 31;
      sm.d.xst[bl*32 + w] = xp[((size_t)tD*128 + bq*32 + bl)*32 + w];
    }
    __syncthreads();
    const int jcol = tid;
    const int dA = Dt[tD*4096 + jcol] + 2048;          // gate i_f col
    const int dB = Dt[tD*4096 + 1024 + jcol] + 2048;   // gate i_n col
    const unsigned dpack = (unsigned)dA | ((unsigned)dB << 16);
    const unsigned long long* mtb = masks + (size_t)tD*131072;
    unsigned acc[32];
    #pragma unroll
    for (int b = 0; b < 32; b++) acc[b] = 0;
    for (int w = 0; w < 32; w++){
      unsigned long long a = mtb[(size_t)w*2048 + jcol];         // coalesced
      unsigned long long g = mtb[(size_t)w*2048 + 1024 + jcol];  // coalesced
      unsigned alo = (unsigned)a, ahi = (unsigned)(a >> 32);
      unsigned glo = (unsigned)g, ghi = (unsigned)(g >> 32);
      #pragma unroll
      for (int b = 0; b < 32; b++){
        unsigned xw = sm.d.xst[b*32 + w];   // wave-uniform broadcast
        acc[b] += __popc(bfi(xw, alo, ahi))
                + (__popc(bfi(xw, glo, ghi)) << 16);
      }
    }
    gbar_nofence(ws, 3u);   // WAR only: all x-mask reads done grid-wide
    unsigned* xgst = xgpool + (size_t)tD*262144;
    #pragma unroll
    for (int b = 0; b < 32; b++)
      xgst[(size_t)(bq*32 + b)*1024 + jcol] = acc[b] + dpack;   // coalesced
  }
  gbar_full(ws, 4u);        // publication: xg visible + stale L2 invalidated

  // ---------- main recurrence
  const int jt = bid & 63, bg = bid >> 6;
  const int j0 = jt * 16, b0 = bg * 32;
  const int kh  = (tid >> 5) & 1;
  const int o   = ((tid >> 6) << 5) + (tid & 31);   // 0..511
  const int b_l = o >> 4, j_l = o & 15;
  const int bglob = b0 + b_l;
  const int w2lo = kh << 3;
  const int jcol = j0 + j_l;

  int hcur = (hx0[(size_t)bglob*1024 + jcol] != 0.0f) ? 1 : 0;
  int A1=0,A2=0,A3=0,A4=0,A5=0,A6=0;
  unsigned sr1=10u, sr2=10u, sr3=10u;
  int i1p=0,i1i=0,i2p=0,i2i=0,i3p=0,i3i=0;

  if (tid < 16) sm.l.rngm[tid] = rngm[tid];

  const unsigned* msrc = (const unsigned*)masks;
  int cur = 0;
  unsigned mreg[2];
  unsigned xg_cur, xg_nxt;

  // ---- prime: stage t=0 hmask, initial h, dh2 table, xg for t=0,1, mreg t=1
  {
    unsigned* mbuf = (unsigned*)sm.l.hmask[0];
    #pragma unroll
    for (int i = 0; i < 2; i++){
      int q = tid + i*NTHR;
      int r = q >> 6, qq = q & 63;
      int c = 2048 + (r >> 4)*1024 + j0 + (r & 15);
      mbuf[r*68 + qq] = msrc[((size_t)0*4096 + c)*64 + qq];
    }
    {
      unsigned long long v = __hip_atomic_load(&hw[(size_t)bg*1024 + tid],
                                               __ATOMIC_RELAXED,
                                               __HIP_MEMORY_SCOPE_AGENT);
      int jt_ = tid >> 4, rp_ = tid & 15;
      unsigned data = (unsigned)v;
      sm.l.hrow16[0][(2*rp_)*68 + jt_]   = (unsigned short)(data & 0xFFFFu);
      sm.l.hrow16[0][(2*rp_+1)*68 + jt_] = (unsigned short)(data >> 16);
    }
    {
      int tt = tid >> 4, jj = tid & 15;    // 1024 threads cover 64 t x 16 j
      sm.l.dh2[(tt*16 + jj)*2 + 0] = Dt[tt*4096 + 2048 + j0 + jj];
      sm.l.dh2[(tt*16 + jj)*2 + 1] = Dt[tt*4096 + 3072 + j0 + jj];
    }
    xg_cur = xgpool[(size_t)0*262144 + (size_t)bglob*1024 + jcol];
    xg_nxt = xgpool[(size_t)1*262144 + (size_t)bglob*1024 + jcol];
    #pragma unroll
    for (int i = 0; i < 2; i++){
      int q = tid + i*NTHR;
      int r = q >> 6, qq = q & 63;
      int c = 2048 + (r >> 4)*1024 + j0 + (r & 15);
      mreg[i] = msrc[((size_t)1*4096 + c)*64 + qq];
    }
    __syncthreads();
  }

  for (int t = 0; t < 64; t++){
    const int par = t & 1;

    // ---- h-gate popc (half-K, bfi form) + wave-local combine
    int s2=0, s3=0;
    {
      const uint2* hrow = (const uint2*)&sm.l.hrow16[cur][b_l*68];
      const ulonglong2* m2p = (const ulonglong2*)&sm.l.hmask[cur][(0  + j_l)*34];
      const ulonglong2* m3p = (const ulonglong2*)&sm.l.hmask[cur][(16 + j_l)*34];
      #pragma unroll
      for (int w2i = 0; w2i < 8; w2i++){
        int w2 = w2lo + w2i;
        uint2 hv = hrow[w2];
        ulonglong2 c2 = m2p[w2];
        s2 += __popc(bfi(hv.x, (unsigned)c2.x, (unsigned)(c2.x >> 32)));
        s2 += __popc(bfi(hv.y, (unsigned)c2.y, (unsigned)(c2.y >> 32)));
        ulonglong2 d = m3p[w2];
        s3 += __popc(bfi(hv.x, (unsigned)d.x, (unsigned)(d.x >> 32)));
        s3 += __popc(bfi(hv.y, (unsigned)d.y, (unsigned)(d.y >> 32)));
      }
    }
    s2 += __shfl_xor(s2, 32);
    s3 += __shfl_xor(s3, 32);
    const int2 dh = *(const int2*)&sm.l.dh2[(t*16 + j_l)*2];
    const int g_hf = dh.x + s2;
    const int g_hn = dh.y + s3;
    const int xgf = (int)(xg_cur & 0xFFFFu) - 2048;
    const int xgn = (int)(xg_cur >> 16) - 2048;

    // ---- FSU elementwise chain (exact, 2x-scaled ints; dup on l, l^32)
    int s1v = xgf + g_hf;
    A1 = clampi(A1 + 2*s1v - 2049);
    int fg_in = (A1 >= 2); A1 -= fg_in << 1;
    A2 = clampi(A2 + ((fg_in + 1) << 1));
    int fg = (A2 >= 4); A2 -= fg << 2;
    A3 = clampi(A3 + (g_hn << 1) - 1024);
    int hnb = (A3 >= 2); A3 -= hnb << 1;

    sr1 = ((sr1 >> 1) | ((unsigned)hnb << 3)) & 0xFu;
    int ng_prod;
    {
      int cv = __popc(sr1) << 2;
      int bp = cv > sm.l.rngm[i1p & 15];
      int bi = cv > sm.l.rngm[i1i & 15];
      ng_prod = fg ? bp : (1 - bi);
      i1p += fg; i1i += 1 - fg;
    }
    A4 = clampi(A4 + (xgn << 1) - 1024);
    int inb = (A4 >= 2); A4 -= inb << 1;
    A5 = clampi(A5 + ((inb + ng_prod) << 1) - 1);
    int ng = (A5 >= 2); A5 -= ng << 1;

    sr2 = ((sr2 >> 1) | ((unsigned)ng << 3)) & 0xFu;
    int fgi;
    {
      int cv = __popc(sr2) << 2;
      int bp = cv > sm.l.rngm[i2p & 15];
      int bi = cv > sm.l.rngm[i2i & 15];
      fgi = (1 - fg) ? bp : (1 - bi);
      i2p += 1 - fg; i2i += fg;
    }
    sr3 = ((sr3 >> 1) | ((unsigned)hcur << 3)) & 0xFu;
    int fgp;
    {
      int cv = __popc(sr3) << 2;
      int bp = cv > sm.l.rngm[i3p & 15];
      int bi = cv > sm.l.rngm[i3i & 15];
      fgp = fg ? bp : (1 - bi);
      i3p += fg; i3i += 1 - fg;
    }
    A6 = clampi(A6 + ((ng + fgi + fgp) << 1) - 2);
    int hy = (A6 >= 2); A6 -= hy << 1;
    hcur = hy;

    if (t < 63){
      unsigned long long bal = __ballot(hy);
      if ((tid & 63) == 0){
        unsigned data = (unsigned)bal;
        unsigned long long val = (unsigned long long)data
                               | ((unsigned long long)(unsigned)(t + 1) << 32);
        __hip_atomic_store(
            &hw[(((size_t)((par ^ 1)*4 + bg))*64 + jt)*16 + (tid >> 6)], val,
            __ATOMIC_RELAXED, __HIP_MEMORY_SCOPE_AGENT);
      }
    }
    if (kh == 0)
      out[(size_t)t*131072 + (size_t)bglob*1024 + jcol] = (float)hy;
    if (t == 63) break;

    // commit prefetched h-mask tile (t+1) into the other buffer
    {
      unsigned* mbuf = (unsigned*)sm.l.hmask[cur ^ 1];
      #pragma unroll
      for (int i = 0; i < 2; i++){
        int q = tid + i*NTHR;
        mbuf[(q >> 6)*68 + (q & 63)] = mreg[i];
      }
    }

    // rotate xg; issue prefetches for t+2
    xg_cur = xg_nxt;
    if (t < 62){
      #pragma unroll
      for (int i = 0; i < 2; i++){
        int q = tid + i*NTHR;
        int r = q >> 6, qq = q & 63;
        int c = 2048 + (r >> 4)*1024 + j0 + (r & 15);
        mreg[i] = msrc[((size_t)(t+2)*4096 + c)*64 + qq];
      }
      xg_nxt = xgpool[(size_t)(t+2)*262144 + (size_t)bglob*1024 + jcol];
    }

    // pull h(t+1): one tagged slot per thread, tag-spin
    {
      const unsigned ep = (unsigned)(t + 1);
      const unsigned long long* slot =
          &hw[((size_t)((par ^ 1)*4 + bg))*1024 + tid];
      unsigned long long v = __hip_atomic_load(slot, __ATOMIC_RELAXED,
                                               __HIP_MEMORY_SCOPE_AGENT);
      while ((unsigned)(v >> 32) < ep){
        __builtin_amdgcn_s_sleep(2);
        v = __hip_atomic_load(slot, __ATOMIC_RELAXED,
                              __HIP_MEMORY_SCOPE_AGENT);
      }
      int jt_ = tid >> 4, rp_ = tid & 15;
      unsigned data = (unsigned)v;
      sm.l.hrow16[cur ^ 1][(2*rp_)*68 + jt_]   = (unsigned short)(data & 0xFFFFu);
      sm.l.hrow16[cur ^ 1][(2*rp_+1)*68 + jt_] = (unsigned short)(data >> 16);
    }
    __syncthreads();   // single barrier per step
    cur ^= 1;
  }
}

extern "C" void kernel_launch(void* const* d_in, const int* in_sizes, int n_in,
                              void* d_out, int out_size, void* d_ws, size_t ws_size,
                              hipStream_t stream)
{
  (void)in_sizes; (void)n_in; (void)out_size; (void)ws_size;
  const float* x   = (const float*)d_in[0];
  const float* hx0 = (const float*)d_in[1];
  const float* wih = (const float*)d_in[2];
  const float* bih = (const float*)d_in[3];
  const float* whh = (const float*)d_in[4];
  const float* bhh = (const float*)d_in[5];
  float* out = (float*)d_out;
  unsigned char* ws = (unsigned char*)d_ws;

  hipMemsetAsync(d_ws, 0, 4096, stream);
  hipMemsetAsync(ws + WS_HW, 0, 65536, stream);

  void* args[] = { (void*)&x, (void*)&hx0, (void*)&wih, (void*)&bih,
                   (void*)&whh, (void*)&bhh, (void*)&out, (void*)&ws };
  hipLaunchCooperativeKernel(reinterpret_cast<void*>(fsu_kernel),
                             dim3(NBLK), dim3(NTHR), args, 0, stream);
}